// Round 1
// baseline (788.505 us; speedup 1.0000x reference)
//
#include <hip/hip_runtime.h>
#include <cstdint>
#include <cstddef>

// ---------------- types ----------------
typedef __bf16 bf16;
typedef __bf16 bf16x8 __attribute__((ext_vector_type(8)));
typedef float  f32x4  __attribute__((ext_vector_type(4)));

#define B_   16
#define N_   1024
#define C_   768
#define H_   12
#define HD_  64
#define M_   (B_*N_)      // 16384 rows
#define MLP_ 3072
#define QKVN 2304         // 3*C

__device__ __forceinline__ void gll16(const void* g, void* l) {
  __builtin_amdgcn_global_load_lds((const __attribute__((address_space(1))) void*)g,
                                   (__attribute__((address_space(3))) void*)l,
                                   16, 0, 0);
}

// ---------------- weight cast + transpose: w[K][N] f32 -> wt[N][K] bf16 ----------------
__global__ void transpose_cast(const float* __restrict__ w, bf16* __restrict__ wt,
                               int K, int N) {
  __shared__ float tile[32][33];
  int n0 = blockIdx.x * 32, k0 = blockIdx.y * 32;
  int tx = threadIdx.x, ty = threadIdx.y;   // block (32,8)
  #pragma unroll
  for (int i = 0; i < 32; i += 8)
    tile[ty + i][tx] = w[(size_t)(k0 + ty + i) * N + n0 + tx];
  __syncthreads();
  #pragma unroll
  for (int i = 0; i < 32; i += 8)
    wt[(size_t)(n0 + ty + i) * K + k0 + tx] = (bf16)tile[tx][ty + i];
}

// ---------------- LayerNorm (768) + cast to bf16 ----------------
__global__ __launch_bounds__(256)
void ln_cast_kernel(const float* __restrict__ x, const float* __restrict__ g,
                    const float* __restrict__ bta, bf16* __restrict__ y) {
  int row = blockIdx.x;
  int tid = threadIdx.x;
  const float* xr = x + (size_t)row * C_;
  float v0 = xr[tid], v1 = xr[tid + 256], v2 = xr[tid + 512];
  float s  = v0 + v1 + v2;
  float sq = v0 * v0 + v1 * v1 + v2 * v2;
  #pragma unroll
  for (int off = 32; off > 0; off >>= 1) {
    s  += __shfl_xor(s,  off);
    sq += __shfl_xor(sq, off);
  }
  __shared__ float red[8];
  int wave = tid >> 6, lane = tid & 63;
  if (lane == 0) { red[wave] = s; red[4 + wave] = sq; }
  __syncthreads();
  s  = red[0] + red[1] + red[2] + red[3];
  sq = red[4] + red[5] + red[6] + red[7];
  float mean = s * (1.0f / C_);
  float var  = sq * (1.0f / C_) - mean * mean;
  float rstd = rsqrtf(var + 1e-5f);
  bf16* yr = y + (size_t)row * C_;
  yr[tid]       = (bf16)((v0 - mean) * rstd * g[tid]       + bta[tid]);
  yr[tid + 256] = (bf16)((v1 - mean) * rstd * g[tid + 256] + bta[tid + 256]);
  yr[tid + 512] = (bf16)((v2 - mean) * rstd * g[tid + 512] + bta[tid + 512]);
}

// ---------------- GEMM: C[M,N] = A[M,K] @ Bt[N,K]^T  (both bf16, fp32 acc) ----------------
// EPI: 0 = store bf16 (qkv) | 1 = x1 = resid + (acc+bias)*ls, f32 (proj)
//      2 = gelu(acc+bias) bf16 (fc1) | 3 = resid + (acc+bias)*ls, f32 (fc2 -> d_out)
template <int EPI>
__global__ __launch_bounds__(256)
void gemm_bt(const bf16* __restrict__ A, const bf16* __restrict__ Bt,
             void* __restrict__ outp, const float* __restrict__ bias,
             const float* __restrict__ ls, const float* __restrict__ resid,
             int M, int N, int K) {
  constexpr int BM = 128, BN = 128, BK = 32;
  __shared__ __align__(16) bf16 As[BM * BK];  // 8 KB
  __shared__ __align__(16) bf16 Bs[BN * BK];  // 8 KB
  int tid  = threadIdx.x;
  int lane = tid & 63, wave = tid >> 6;
  int quad = lane >> 4, l16 = lane & 15;
  int m0 = blockIdx.y * BM, n0 = blockIdx.x * BN;
  int wm = (wave >> 1) * 64, wn = (wave & 1) * 64;

  // staging: load u (u = tid, tid+256) covers LDS row u/4, cols (u%4)*8..+7
  const bf16* Ag = A  + (size_t)(m0 + tid / 4) * K + (tid % 4) * 8;
  const bf16* Bg = Bt + (size_t)(n0 + tid / 4) * K + (tid % 4) * 8;

  const f32x4 fz = {0.f, 0.f, 0.f, 0.f};
  f32x4 acc[4][4];
  #pragma unroll
  for (int i = 0; i < 4; i++)
    #pragma unroll
    for (int j = 0; j < 4; j++) acc[i][j] = fz;

  for (int k0 = 0; k0 < K; k0 += BK) {
    gll16(Ag + k0,            As + tid * 8);
    gll16(Ag + 64 * K + k0,   As + 2048 + tid * 8);
    gll16(Bg + k0,            Bs + tid * 8);
    gll16(Bg + 64 * K + k0,   Bs + 2048 + tid * 8);
    __syncthreads();   // drains vmcnt: tiles staged
    bf16x8 af[4], bfr[4];
    #pragma unroll
    for (int i = 0; i < 4; i++)
      af[i] = *(const bf16x8*)(As + (wm + i * 16 + l16) * BK + quad * 8);
    #pragma unroll
    for (int j = 0; j < 4; j++)
      bfr[j] = *(const bf16x8*)(Bs + (wn + j * 16 + l16) * BK + quad * 8);
    #pragma unroll
    for (int i = 0; i < 4; i++)
      #pragma unroll
      for (int j = 0; j < 4; j++)
        acc[i][j] = __builtin_amdgcn_mfma_f32_16x16x32_bf16(af[i], bfr[j], acc[i][j], 0, 0, 0);
    __syncthreads();   // all reads done before next stage overwrites
  }

  // epilogue: D[row][col], row = quad*4 + reg, col = lane&15 (per 16x16 frag)
  #pragma unroll
  for (int i = 0; i < 4; i++) {
    int rowb = m0 + wm + i * 16 + quad * 4;
    #pragma unroll
    for (int j = 0; j < 4; j++) {
      int col = n0 + wn + j * 16 + l16;
      #pragma unroll
      for (int r = 0; r < 4; r++) {
        float v = acc[i][j][r];
        size_t idx = (size_t)(rowb + r) * N + col;
        if constexpr (EPI == 0) {
          ((bf16*)outp)[idx] = (bf16)v;
        } else if constexpr (EPI == 1) {
          ((float*)outp)[idx] = resid[idx] + (v + bias[col]) * ls[col];
        } else if constexpr (EPI == 2) {
          float t = v + bias[col];
          ((bf16*)outp)[idx] = (bf16)(0.5f * t * (1.0f + erff(t * 0.70710678118f)));
        } else {
          ((float*)outp)[idx] = resid[idx] + (v + bias[col]) * ls[col];
        }
      }
    }
  }
}

// ---------------- V transpose: qkv[.,1536+h*64+d] -> vt[bh][d][n] ----------------
__global__ void transpose_v(const bf16* __restrict__ qkv, bf16* __restrict__ vt) {
  __shared__ bf16 tile[32][33];
  int bh = blockIdx.z;
  int b = bh / H_, h = bh % H_;
  int n0 = blockIdx.x * 32, d0 = blockIdx.y * 32;
  int tx = threadIdx.x, ty = threadIdx.y;   // block (32,8)
  const bf16* src = qkv + (size_t)(b * N_) * QKVN + 2 * C_ + h * HD_;
  #pragma unroll
  for (int i = 0; i < 32; i += 8)
    tile[ty + i][tx] = src[(size_t)(n0 + ty + i) * QKVN + d0 + tx];
  __syncthreads();
  bf16* dst = vt + (size_t)bh * HD_ * N_;
  #pragma unroll
  for (int i = 0; i < 32; i += 8)
    dst[(size_t)(d0 + ty + i) * N_ + n0 + tx] = tile[tx][ty + i];
}

// ---------------- flash attention ----------------
// grid (N/128, B*H), block 256. 4 waves x 32 q-rows. Online softmax.
__global__ __launch_bounds__(256)
void attn_kernel(const bf16* __restrict__ qkv, const bf16* __restrict__ vt,
                 bf16* __restrict__ o) {
  constexpr int KSTR = 72;    // K tile stride (64 + 8 pad)
  constexpr int VSTR = 136;   // Vt tile stride (128 + 8 pad)
  constexpr int PSTR = 136;   // P tile stride
  __shared__ __align__(16) bf16 KVs[128 * KSTR];   // 18432 B; Vt alias needs 64*136=8704 el
  __shared__ __align__(16) bf16 Ps[128 * PSTR];    // 34816 B

  int tid = threadIdx.x, lane = tid & 63, wave = tid >> 6;
  int quad = lane >> 4, l16 = lane & 15;
  int bh = blockIdx.y;
  int b = bh / H_, h = bh % H_;
  int q0 = blockIdx.x * 128;
  const float scale = 0.125f;   // HD^-0.5

  // Q fragments in registers: rows q0 + wave*32 + i*16 + l16, k = kk*32 + quad*8
  bf16x8 qf[2][2];
  #pragma unroll
  for (int i = 0; i < 2; i++)
    #pragma unroll
    for (int kk = 0; kk < 2; kk++)
      qf[i][kk] = *(const bf16x8*)(qkv + (size_t)(b * N_ + q0 + wave * 32 + i * 16 + l16) * QKVN
                                   + h * HD_ + kk * 32 + quad * 8);

  const f32x4 fz = {0.f, 0.f, 0.f, 0.f};
  f32x4 oacc[2][4];
  float m_run[2][4], l_run[2][4];
  #pragma unroll
  for (int i = 0; i < 2; i++) {
    #pragma unroll
    for (int jd = 0; jd < 4; jd++) oacc[i][jd] = fz;
    #pragma unroll
    for (int r = 0; r < 4; r++) { m_run[i][r] = -1e30f; l_run[i][r] = 0.f; }
  }

  const bf16* kbase = qkv + (size_t)(b * N_) * QKVN + C_ + h * HD_;
  const bf16* vbase = vt + (size_t)bh * HD_ * N_;

  for (int kv = 0; kv < N_; kv += 128) {
    __syncthreads();   // prior-iter Vt reads done -> safe to overwrite KVs
    // stage K tile [128 keys][64 d] with padded stride
    #pragma unroll
    for (int u = 0; u < 4; u++) {
      int L = tid + u * 256;
      int r = L >> 3, c = (L & 7) * 8;
      *(bf16x8*)(KVs + r * KSTR + c) =
          *(const bf16x8*)(kbase + (size_t)(kv + r) * QKVN + c);
    }
    __syncthreads();

    // S = (Q @ K^T): per wave 32 q x 128 keys
    f32x4 sv[2][8];
    #pragma unroll
    for (int i = 0; i < 2; i++)
      #pragma unroll
      for (int kf = 0; kf < 8; kf++) sv[i][kf] = fz;
    #pragma unroll
    for (int kk = 0; kk < 2; kk++) {
      #pragma unroll
      for (int kf = 0; kf < 8; kf++) {
        bf16x8 kb = *(const bf16x8*)(KVs + (kf * 16 + l16) * KSTR + kk * 32 + quad * 8);
        sv[0][kf] = __builtin_amdgcn_mfma_f32_16x16x32_bf16(qf[0][kk], kb, sv[0][kf], 0, 0, 0);
        sv[1][kf] = __builtin_amdgcn_mfma_f32_16x16x32_bf16(qf[1][kk], kb, sv[1][kf], 0, 0, 0);
      }
    }

    // online softmax (rows = quad*4 + r within each 16x16 frag)
    #pragma unroll
    for (int i = 0; i < 2; i++) {
      #pragma unroll
      for (int kf = 0; kf < 8; kf++) sv[i][kf] *= scale;
      #pragma unroll
      for (int r = 0; r < 4; r++) {
        float mx = sv[i][0][r];
        #pragma unroll
        for (int kf = 1; kf < 8; kf++) mx = fmaxf(mx, sv[i][kf][r]);
        #pragma unroll
        for (int off = 1; off < 16; off <<= 1) mx = fmaxf(mx, __shfl_xor(mx, off));
        float mold = m_run[i][r];
        float mnew = fmaxf(mold, mx);
        float al   = __expf(mold - mnew);
        float rs = 0.f;
        #pragma unroll
        for (int kf = 0; kf < 8; kf++) {
          float p = __expf(sv[i][kf][r] - mnew);
          sv[i][kf][r] = p;
          rs += p;
        }
        #pragma unroll
        for (int off = 1; off < 16; off <<= 1) rs += __shfl_xor(rs, off);
        m_run[i][r] = mnew;
        l_run[i][r] = l_run[i][r] * al + rs;
        #pragma unroll
        for (int jd = 0; jd < 4; jd++) oacc[i][jd][r] *= al;
        int prow = wave * 32 + i * 16 + quad * 4 + r;
        #pragma unroll
        for (int kf = 0; kf < 8; kf++)
          Ps[prow * PSTR + kf * 16 + l16] = (bf16)sv[i][kf][r];
      }
    }

    __syncthreads();   // all waves done reading K tile
    // stage Vt tile [64 d][128 keys] into alias region
    #pragma unroll
    for (int u = 0; u < 4; u++) {
      int L = tid + u * 256;
      int r = L >> 4, c = (L & 15) * 8;
      *(bf16x8*)(KVs + r * VSTR + c) =
          *(const bf16x8*)(vbase + (size_t)r * N_ + kv + c);
    }
    __syncthreads();

    // O += P @ V  (a-frags from own rows of Ps — same-wave write/read, no barrier)
    #pragma unroll
    for (int kc = 0; kc < 4; kc++) {
      bf16x8 pa0 = *(const bf16x8*)(Ps + (wave * 32 + l16) * PSTR + kc * 32 + quad * 8);
      bf16x8 pa1 = *(const bf16x8*)(Ps + (wave * 32 + 16 + l16) * PSTR + kc * 32 + quad * 8);
      #pragma unroll
      for (int jd = 0; jd < 4; jd++) {
        bf16x8 vb = *(const bf16x8*)(KVs + (jd * 16 + l16) * VSTR + kc * 32 + quad * 8);
        oacc[0][jd] = __builtin_amdgcn_mfma_f32_16x16x32_bf16(pa0, vb, oacc[0][jd], 0, 0, 0);
        oacc[1][jd] = __builtin_amdgcn_mfma_f32_16x16x32_bf16(pa1, vb, oacc[1][jd], 0, 0, 0);
      }
    }
  }

  // finalize: divide by l, store o[b,n,h*64+d] bf16
  #pragma unroll
  for (int i = 0; i < 2; i++) {
    #pragma unroll
    for (int r = 0; r < 4; r++) {
      float inv = 1.0f / l_run[i][r];
      int n = q0 + wave * 32 + i * 16 + quad * 4 + r;
      #pragma unroll
      for (int jd = 0; jd < 4; jd++)
        o[(size_t)(b * N_ + n) * C_ + h * HD_ + jd * 16 + l16] = (bf16)(oacc[i][jd][r] * inv);
    }
  }
}

// ---------------- host: workspace layout + launch ----------------
#define WQKVT_OFF  0u
#define WPROJT_OFF 3538944u
#define WFC1T_OFF  4718592u
#define WFC2T_OFF  9437184u
#define Y_OFF      14155776u
#define QKV_OFF    39321600u    // also reused for MLP hidden h (100663296 B)
#define VT_OFF     139984896u
#define O_OFF      165150720u
#define X1_OFF     190316544u
#define WS_NEEDED  240648192u

extern "C" void kernel_launch(void* const* d_in, const int* in_sizes, int n_in,
                              void* d_out, int out_size, void* d_ws, size_t ws_size,
                              hipStream_t stream) {
  if (ws_size < (size_t)WS_NEEDED) return;  // insufficient scratch -> clean failure

  const float* x      = (const float*)d_in[0];
  const float* w_qkv  = (const float*)d_in[1];
  const float* w_proj = (const float*)d_in[2];
  const float* b_proj = (const float*)d_in[3];
  const float* ln1_g  = (const float*)d_in[4];
  const float* ln1_b  = (const float*)d_in[5];
  const float* ln2_g  = (const float*)d_in[6];
  const float* ln2_b  = (const float*)d_in[7];
  const float* ls1_g  = (const float*)d_in[8];
  const float* ls2_g  = (const float*)d_in[9];
  const float* w_fc1  = (const float*)d_in[10];
  const float* b_fc1  = (const float*)d_in[11];
  const float* w_fc2  = (const float*)d_in[12];
  const float* b_fc2  = (const float*)d_in[13];

  char* ws = (char*)d_ws;
  bf16*  wqkvT  = (bf16*)(ws + WQKVT_OFF);
  bf16*  wprojT = (bf16*)(ws + WPROJT_OFF);
  bf16*  wfc1T  = (bf16*)(ws + WFC1T_OFF);
  bf16*  wfc2T  = (bf16*)(ws + WFC2T_OFF);
  bf16*  y      = (bf16*)(ws + Y_OFF);
  bf16*  qkv    = (bf16*)(ws + QKV_OFF);
  bf16*  hbuf   = (bf16*)(ws + QKV_OFF);   // alias: qkv dead after attention
  bf16*  vt     = (bf16*)(ws + VT_OFF);
  bf16*  o      = (bf16*)(ws + O_OFF);
  float* x1     = (float*)(ws + X1_OFF);
  float* out    = (float*)d_out;

  dim3 tb(32, 8);
  // weights -> bf16 transposed [N][K]
  transpose_cast<<<dim3(QKVN / 32, C_ / 32), tb, 0, stream>>>(w_qkv,  wqkvT,  C_,   QKVN);
  transpose_cast<<<dim3(C_   / 32, C_ / 32), tb, 0, stream>>>(w_proj, wprojT, C_,   C_);
  transpose_cast<<<dim3(MLP_ / 32, C_ / 32), tb, 0, stream>>>(w_fc1,  wfc1T,  C_,   MLP_);
  transpose_cast<<<dim3(C_ / 32, MLP_ / 32), tb, 0, stream>>>(w_fc2,  wfc2T,  MLP_, C_);

  // LN1 -> y (bf16)
  ln_cast_kernel<<<M_, 256, 0, stream>>>(x, ln1_g, ln1_b, y);

  // qkv = y @ w_qkv  (bf16 out)
  gemm_bt<0><<<dim3(QKVN / 128, M_ / 128), 256, 0, stream>>>(
      y, wqkvT, qkv, nullptr, nullptr, nullptr, M_, QKVN, C_);

  // V transpose -> vt[bh][d][n]
  transpose_v<<<dim3(N_ / 32, HD_ / 32, B_ * H_), tb, 0, stream>>>(qkv, vt);

  // attention -> o (bf16)
  attn_kernel<<<dim3(N_ / 128, B_ * H_), 256, 0, stream>>>(qkv, vt, o);

  // x1 = x + (o @ w_proj + b_proj) * ls1
  gemm_bt<1><<<dim3(C_ / 128, M_ / 128), 256, 0, stream>>>(
      o, wprojT, x1, b_proj, ls1_g, x, M_, C_, C_);

  // LN2 -> y (bf16, reuse buffer)
  ln_cast_kernel<<<M_, 256, 0, stream>>>(x1, ln2_g, ln2_b, y);

  // h = gelu(y @ w_fc1 + b_fc1)  (bf16, reuses qkv slot)
  gemm_bt<2><<<dim3(MLP_ / 128, M_ / 128), 256, 0, stream>>>(
      y, wfc1T, hbuf, b_fc1, nullptr, nullptr, M_, MLP_, C_);

  // out = x1 + (h @ w_fc2 + b_fc2) * ls2
  gemm_bt<3><<<dim3(C_ / 128, M_ / 128), 256, 0, stream>>>(
      hbuf, wfc2T, out, b_fc2, ls2_g, x1, M_, C_, MLP_);
}

// Round 2
// 764.880 us; speedup vs baseline: 1.0309x; 1.0309x over previous
//
#include <hip/hip_runtime.h>
#include <cstdint>
#include <cstddef>

// ---------------- types ----------------
typedef __bf16 bf16;
typedef __bf16 bf16x4 __attribute__((ext_vector_type(4)));
typedef __bf16 bf16x8 __attribute__((ext_vector_type(8)));
typedef _Float16 f16;
typedef _Float16 f16x4 __attribute__((ext_vector_type(4)));
typedef _Float16 f16x8 __attribute__((ext_vector_type(8)));
typedef float  f32x4  __attribute__((ext_vector_type(4)));

#define B_   16
#define N_   1024
#define C_   768
#define H_   12
#define HD_  64
#define M_   (B_*N_)      // 16384 rows
#define MLP_ 3072
#define QKVN 2304         // 3*C

__device__ __forceinline__ void gll16(const void* g, void* l) {
  __builtin_amdgcn_global_load_lds((const __attribute__((address_space(1))) void*)g,
                                   (__attribute__((address_space(3))) void*)l,
                                   16, 0, 0);
}

// ---------------- weight cast + transpose: w[K][N] f32 -> wt[N][K] bf16 ----------------
__global__ void transpose_cast(const float* __restrict__ w, bf16* __restrict__ wt,
                               int K, int N) {
  __shared__ float tile[32][33];
  int n0 = blockIdx.x * 32, k0 = blockIdx.y * 32;
  int tx = threadIdx.x, ty = threadIdx.y;   // block (32,8)
  #pragma unroll
  for (int i = 0; i < 32; i += 8)
    tile[ty + i][tx] = w[(size_t)(k0 + ty + i) * N + n0 + tx];
  __syncthreads();
  #pragma unroll
  for (int i = 0; i < 32; i += 8)
    wt[(size_t)(n0 + ty + i) * K + k0 + tx] = (bf16)tile[tx][ty + i];
}

// ---------------- LayerNorm (768) + cast to bf16 ----------------
__global__ __launch_bounds__(256)
void ln_cast_kernel(const float* __restrict__ x, const float* __restrict__ g,
                    const float* __restrict__ bta, bf16* __restrict__ y) {
  int row = blockIdx.x;
  int tid = threadIdx.x;
  const float* xr = x + (size_t)row * C_;
  float v0 = xr[tid], v1 = xr[tid + 256], v2 = xr[tid + 512];
  float s  = v0 + v1 + v2;
  float sq = v0 * v0 + v1 * v1 + v2 * v2;
  #pragma unroll
  for (int off = 32; off > 0; off >>= 1) {
    s  += __shfl_xor(s,  off);
    sq += __shfl_xor(sq, off);
  }
  __shared__ float red[8];
  int wave = tid >> 6, lane = tid & 63;
  if (lane == 0) { red[wave] = s; red[4 + wave] = sq; }
  __syncthreads();
  s  = red[0] + red[1] + red[2] + red[3];
  sq = red[4] + red[5] + red[6] + red[7];
  float mean = s * (1.0f / C_);
  float var  = sq * (1.0f / C_) - mean * mean;
  float rstd = rsqrtf(var + 1e-5f);
  bf16* yr = y + (size_t)row * C_;
  yr[tid]       = (bf16)((v0 - mean) * rstd * g[tid]       + bta[tid]);
  yr[tid + 256] = (bf16)((v1 - mean) * rstd * g[tid + 256] + bta[tid + 256]);
  yr[tid + 512] = (bf16)((v2 - mean) * rstd * g[tid + 512] + bta[tid + 512]);
}

// ---------------- GEMM: C[M,N] = A[M,K] @ Bt[N,K]^T  (both bf16, fp32 acc) ----------------
// EPI: 0 = store bf16 (qkv) | 1 = x1 = resid + (acc+bias)*ls, f32 (proj)
//      2 = gelu(acc+bias) bf16 (fc1) | 3 = resid + (acc+bias)*ls, f32 (fc2 -> d_out)
template <int EPI>
__global__ __launch_bounds__(256)
void gemm_bt(const bf16* __restrict__ A, const bf16* __restrict__ Bt,
             void* __restrict__ outp, const float* __restrict__ bias,
             const float* __restrict__ ls, const float* __restrict__ resid,
             int M, int N, int K) {
  constexpr int BM = 128, BN = 128, BK = 32;
  __shared__ __align__(16) bf16 As[BM * BK];  // 8 KB
  __shared__ __align__(16) bf16 Bs[BN * BK];  // 8 KB
  int tid  = threadIdx.x;
  int lane = tid & 63, wave = tid >> 6;
  int quad = lane >> 4, l16 = lane & 15;
  int m0 = blockIdx.y * BM, n0 = blockIdx.x * BN;
  int wm = (wave >> 1) * 64, wn = (wave & 1) * 64;

  const bf16* Ag = A  + (size_t)(m0 + tid / 4) * K + (tid % 4) * 8;
  const bf16* Bg = Bt + (size_t)(n0 + tid / 4) * K + (tid % 4) * 8;

  const f32x4 fz = {0.f, 0.f, 0.f, 0.f};
  f32x4 acc[4][4];
  #pragma unroll
  for (int i = 0; i < 4; i++)
    #pragma unroll
    for (int j = 0; j < 4; j++) acc[i][j] = fz;

  for (int k0 = 0; k0 < K; k0 += BK) {
    gll16(Ag + k0,            As + tid * 8);
    gll16(Ag + 64 * K + k0,   As + 2048 + tid * 8);
    gll16(Bg + k0,            Bs + tid * 8);
    gll16(Bg + 64 * K + k0,   Bs + 2048 + tid * 8);
    __syncthreads();
    bf16x8 af[4], bfr[4];
    #pragma unroll
    for (int i = 0; i < 4; i++)
      af[i] = *(const bf16x8*)(As + (wm + i * 16 + l16) * BK + quad * 8);
    #pragma unroll
    for (int j = 0; j < 4; j++)
      bfr[j] = *(const bf16x8*)(Bs + (wn + j * 16 + l16) * BK + quad * 8);
    #pragma unroll
    for (int i = 0; i < 4; i++)
      #pragma unroll
      for (int j = 0; j < 4; j++)
        acc[i][j] = __builtin_amdgcn_mfma_f32_16x16x32_bf16(af[i], bfr[j], acc[i][j], 0, 0, 0);
    __syncthreads();
  }

  #pragma unroll
  for (int i = 0; i < 4; i++) {
    int rowb = m0 + wm + i * 16 + quad * 4;
    #pragma unroll
    for (int j = 0; j < 4; j++) {
      int col = n0 + wn + j * 16 + l16;
      #pragma unroll
      for (int r = 0; r < 4; r++) {
        float v = acc[i][j][r];
        size_t idx = (size_t)(rowb + r) * N + col;
        if constexpr (EPI == 0) {
          ((bf16*)outp)[idx] = (bf16)v;
        } else if constexpr (EPI == 1) {
          ((float*)outp)[idx] = resid[idx] + (v + bias[col]) * ls[col];
        } else if constexpr (EPI == 2) {
          float t = v + bias[col];
          ((bf16*)outp)[idx] = (bf16)(0.5f * t * (1.0f + erff(t * 0.70710678118f)));
        } else {
          ((float*)outp)[idx] = resid[idx] + (v + bias[col]) * ls[col];
        }
      }
    }
  }
}

// ---------------- V transpose: qkv[.,1536+h*64+d] bf16 -> vt[bh][d][n] f16 ----------------
__global__ void transpose_v(const bf16* __restrict__ qkv, f16* __restrict__ vt) {
  __shared__ bf16 tile[32][33];
  int bh = blockIdx.z;
  int b = bh / H_, h = bh % H_;
  int n0 = blockIdx.x * 32, d0 = blockIdx.y * 32;
  int tx = threadIdx.x, ty = threadIdx.y;   // block (32,8)
  const bf16* src = qkv + (size_t)(b * N_) * QKVN + 2 * C_ + h * HD_;
  #pragma unroll
  for (int i = 0; i < 32; i += 8)
    tile[ty + i][tx] = src[(size_t)(n0 + ty + i) * QKVN + d0 + tx];
  __syncthreads();
  f16* dst = vt + (size_t)bh * HD_ * N_;
  #pragma unroll
  for (int i = 0; i < 32; i += 8)
    dst[(size_t)(d0 + ty + i) * N_ + n0 + tx] = (f16)(float)tile[tx][ty + i];
}

// ---------------- flash attention, S^T formulation ----------------
// S^T = K @ Q^T  (C-layout: key = quad*4+r, q = l16) -> softmax is register-local
// over keys + 2 shuffles.  exp'd S^T regs ARE the B-operand of 16x16x16 f16 MFMA
// (B[n=l16][k=quad*4+j]) -> PV as O^T = V^T @ P^T with zero P data movement.
__global__ __launch_bounds__(256)
void attn_kernel(const bf16* __restrict__ qkv, const f16* __restrict__ vt,
                 bf16* __restrict__ o) {
  constexpr int KSTR = 72;    // K tile stride (64 + 8 pad), bf16
  constexpr int VSTR = 136;   // V^T tile stride (128 + 8 pad), f16
  __shared__ __align__(16) bf16 Ks[128 * KSTR];   // 18432 B
  __shared__ __align__(16) f16  Vs[HD_ * VSTR];   // 17408 B

  int tid = threadIdx.x, lane = tid & 63, wave = tid >> 6;
  int quad = lane >> 4, l16 = lane & 15;
  int bh = blockIdx.y;
  int b = bh / H_, h = bh % H_;
  int q0 = blockIdx.x * 128;
  const float CEXP = 0.125f * 1.44269504f;   // scale * log2(e)

  // Q fragments (B-operand): lane holds Q[q=l16][d=quad*8+j], per (i, kk)
  bf16x8 qf[2][2];
  #pragma unroll
  for (int i = 0; i < 2; i++)
    #pragma unroll
    for (int kk = 0; kk < 2; kk++)
      qf[i][kk] = *(const bf16x8*)(qkv + (size_t)(b * N_ + q0 + wave * 32 + i * 16 + l16) * QKVN
                                   + h * HD_ + kk * 32 + quad * 8);

  const f32x4 fz = {0.f, 0.f, 0.f, 0.f};
  f32x4 oacc[2][4];            // [q-frag i][d-frag jd]: O^T[d=quad*4+r][q=l16]
  float m_run[2], l_run[2];
  #pragma unroll
  for (int i = 0; i < 2; i++) {
    #pragma unroll
    for (int jd = 0; jd < 4; jd++) oacc[i][jd] = fz;
    m_run[i] = -1e30f; l_run[i] = 0.f;
  }

  const bf16* kbase = qkv + (size_t)(b * N_) * QKVN + C_ + h * HD_;
  const f16*  vbase = vt + (size_t)bh * HD_ * N_;

  for (int kv = 0; kv < N_; kv += 128) {
    __syncthreads();   // prior-iter Ks/Vs reads complete
    // stage K tile [128 keys][64 d] bf16
    #pragma unroll
    for (int u = 0; u < 4; u++) {
      int L = tid + u * 256;
      int r = L >> 3, c = (L & 7) * 8;
      *(bf16x8*)(Ks + r * KSTR + c) =
          *(const bf16x8*)(kbase + (size_t)(kv + r) * QKVN + c);
    }
    // stage V^T tile [64 d][128 keys] f16
    #pragma unroll
    for (int u = 0; u < 4; u++) {
      int L = tid + u * 256;
      int r = L >> 4, c = (L & 15) * 8;
      *(f16x8*)(Vs + r * VSTR + c) =
          *(const f16x8*)(vbase + (size_t)r * N_ + kv + c);
    }
    __syncthreads();

    // S^T = K @ Q^T : sv[i][kf] holds S^T[key = kf*16 + quad*4 + r][q = l16]
    f32x4 sv[2][8];
    #pragma unroll
    for (int i = 0; i < 2; i++)
      #pragma unroll
      for (int kf = 0; kf < 8; kf++) sv[i][kf] = fz;
    #pragma unroll
    for (int kk = 0; kk < 2; kk++) {
      #pragma unroll
      for (int kf = 0; kf < 8; kf++) {
        bf16x8 kb = *(const bf16x8*)(Ks + (kf * 16 + l16) * KSTR + kk * 32 + quad * 8);
        sv[0][kf] = __builtin_amdgcn_mfma_f32_16x16x32_bf16(kb, qf[0][kk], sv[0][kf], 0, 0, 0);
        sv[1][kf] = __builtin_amdgcn_mfma_f32_16x16x32_bf16(kb, qf[1][kk], sv[1][kf], 0, 0, 0);
      }
    }

    // online softmax per q-frag: keys live in registers, queries on l16
    f16x4 pb[2][8];
    #pragma unroll
    for (int i = 0; i < 2; i++) {
      float mx = sv[i][0][0];
      #pragma unroll
      for (int kf = 0; kf < 8; kf++)
        #pragma unroll
        for (int r = 0; r < 4; r++) mx = fmaxf(mx, sv[i][kf][r]);
      mx = fmaxf(mx, __shfl_xor(mx, 16));
      mx = fmaxf(mx, __shfl_xor(mx, 32));
      float mold = m_run[i];
      float mnew = fmaxf(mold, mx);
      float mb   = mnew * CEXP;
      float al   = exp2f(mold * CEXP - mb);
      float rs = 0.f;
      #pragma unroll
      for (int kf = 0; kf < 8; kf++) {
        #pragma unroll
        for (int r = 0; r < 4; r++) {
          float p = exp2f(sv[i][kf][r] * CEXP - mb);
          pb[i][kf][r] = (f16)p;
          rs += p;
        }
      }
      rs += __shfl_xor(rs, 16);
      rs += __shfl_xor(rs, 32);
      m_run[i] = mnew;
      l_run[i] = l_run[i] * al + rs;
      #pragma unroll
      for (int jd = 0; jd < 4; jd++) oacc[i][jd] *= al;
    }

    // O^T += V^T @ P^T  (A = V^T from LDS, B = pb registers)
    #pragma unroll
    for (int kc = 0; kc < 8; kc++) {
      #pragma unroll
      for (int jd = 0; jd < 4; jd++) {
        f16x4 va = *(const f16x4*)(Vs + (jd * 16 + l16) * VSTR + kc * 16 + quad * 4);
        oacc[0][jd] = __builtin_amdgcn_mfma_f32_16x16x16f16(va, pb[0][kc], oacc[0][jd], 0, 0, 0);
        oacc[1][jd] = __builtin_amdgcn_mfma_f32_16x16x16f16(va, pb[1][kc], oacc[1][jd], 0, 0, 0);
      }
    }
  }

  // finalize: O = O^T / l, packed 8B stores (4 contiguous d per lane)
  #pragma unroll
  for (int i = 0; i < 2; i++) {
    float inv = 1.0f / l_run[i];
    int n = q0 + wave * 32 + i * 16 + l16;
    #pragma unroll
    for (int jd = 0; jd < 4; jd++) {
      bf16x4 ov;
      #pragma unroll
      for (int r = 0; r < 4; r++) ov[r] = (bf16)(oacc[i][jd][r] * inv);
      *(bf16x4*)(o + (size_t)(b * N_ + n) * C_ + h * HD_ + jd * 16 + quad * 4) = ov;
    }
  }
}

// ---------------- host: workspace layout + launch ----------------
#define WQKVT_OFF  0u
#define WPROJT_OFF 3538944u
#define WFC1T_OFF  4718592u
#define WFC2T_OFF  9437184u
#define Y_OFF      14155776u
#define QKV_OFF    39321600u    // also reused for MLP hidden h (100663296 B)
#define VT_OFF     139984896u
#define O_OFF      165150720u
#define X1_OFF     190316544u
#define WS_NEEDED  240648192u

extern "C" void kernel_launch(void* const* d_in, const int* in_sizes, int n_in,
                              void* d_out, int out_size, void* d_ws, size_t ws_size,
                              hipStream_t stream) {
  if (ws_size < (size_t)WS_NEEDED) return;

  const float* x      = (const float*)d_in[0];
  const float* w_qkv  = (const float*)d_in[1];
  const float* w_proj = (const float*)d_in[2];
  const float* b_proj = (const float*)d_in[3];
  const float* ln1_g  = (const float*)d_in[4];
  const float* ln1_b  = (const float*)d_in[5];
  const float* ln2_g  = (const float*)d_in[6];
  const float* ln2_b  = (const float*)d_in[7];
  const float* ls1_g  = (const float*)d_in[8];
  const float* ls2_g  = (const float*)d_in[9];
  const float* w_fc1  = (const float*)d_in[10];
  const float* b_fc1  = (const float*)d_in[11];
  const float* w_fc2  = (const float*)d_in[12];
  const float* b_fc2  = (const float*)d_in[13];

  char* ws = (char*)d_ws;
  bf16*  wqkvT  = (bf16*)(ws + WQKVT_OFF);
  bf16*  wprojT = (bf16*)(ws + WPROJT_OFF);
  bf16*  wfc1T  = (bf16*)(ws + WFC1T_OFF);
  bf16*  wfc2T  = (bf16*)(ws + WFC2T_OFF);
  bf16*  y      = (bf16*)(ws + Y_OFF);
  bf16*  qkv    = (bf16*)(ws + QKV_OFF);
  bf16*  hbuf   = (bf16*)(ws + QKV_OFF);   // alias: qkv dead after attention
  f16*   vt     = (f16*)(ws + VT_OFF);
  bf16*  o      = (bf16*)(ws + O_OFF);
  float* x1     = (float*)(ws + X1_OFF);
  float* out    = (float*)d_out;

  dim3 tb(32, 8);
  transpose_cast<<<dim3(QKVN / 32, C_ / 32), tb, 0, stream>>>(w_qkv,  wqkvT,  C_,   QKVN);
  transpose_cast<<<dim3(C_   / 32, C_ / 32), tb, 0, stream>>>(w_proj, wprojT, C_,   C_);
  transpose_cast<<<dim3(MLP_ / 32, C_ / 32), tb, 0, stream>>>(w_fc1,  wfc1T,  C_,   MLP_);
  transpose_cast<<<dim3(C_ / 32, MLP_ / 32), tb, 0, stream>>>(w_fc2,  wfc2T,  MLP_, C_);

  ln_cast_kernel<<<M_, 256, 0, stream>>>(x, ln1_g, ln1_b, y);

  gemm_bt<0><<<dim3(QKVN / 128, M_ / 128), 256, 0, stream>>>(
      y, wqkvT, qkv, nullptr, nullptr, nullptr, M_, QKVN, C_);

  transpose_v<<<dim3(N_ / 32, HD_ / 32, B_ * H_), tb, 0, stream>>>(qkv, vt);

  attn_kernel<<<dim3(N_ / 128, B_ * H_), 256, 0, stream>>>(qkv, vt, o);

  gemm_bt<1><<<dim3(C_ / 128, M_ / 128), 256, 0, stream>>>(
      o, wprojT, x1, b_proj, ls1_g, x, M_, C_, C_);

  ln_cast_kernel<<<M_, 256, 0, stream>>>(x1, ln2_g, ln2_b, y);

  gemm_bt<2><<<dim3(MLP_ / 128, M_ / 128), 256, 0, stream>>>(
      y, wfc1T, hbuf, b_fc1, nullptr, nullptr, M_, MLP_, C_);

  gemm_bt<3><<<dim3(C_ / 128, M_ / 128), 256, 0, stream>>>(
      hbuf, wfc2T, out, b_fc2, ls2_g, x1, M_, C_, MLP_);
}

// Round 3
// 617.813 us; speedup vs baseline: 1.2763x; 1.2380x over previous
//
#include <hip/hip_runtime.h>
#include <cstdint>
#include <cstddef>

// ---------------- types ----------------
typedef __bf16 bf16;
typedef __bf16 bf16x4 __attribute__((ext_vector_type(4)));
typedef __bf16 bf16x8 __attribute__((ext_vector_type(8)));
typedef _Float16 f16;
typedef _Float16 f16x4 __attribute__((ext_vector_type(4)));
typedef _Float16 f16x8 __attribute__((ext_vector_type(8)));
typedef float  f32x4  __attribute__((ext_vector_type(4)));
typedef unsigned char u8;

#define B_   16
#define N_   1024
#define C_   768
#define H_   12
#define HD_  64
#define M_   (B_*N_)      // 16384 rows
#define MLP_ 3072
#define QKVN 2304         // 3*C
#define WSCALE 64.0f      // weights cast to fp8 at x64 (0.02-scale weights are subnormal in e4m3)
#define WINV  (1.0f/64.0f)

__device__ __forceinline__ void gll16(const void* g, void* l) {
  __builtin_amdgcn_global_load_lds((const __attribute__((address_space(1))) void*)g,
                                   (__attribute__((address_space(3))) void*)l,
                                   16, 0, 0);
}

// fp8 e4m3 (OCP on gfx950) converts via HW packed cvt
__device__ __forceinline__ u8 to_fp8(float a) {
  return (u8)(__builtin_amdgcn_cvt_pk_fp8_f32(a, a, 0, false) & 0xff);
}
__device__ __forceinline__ int to_fp8x4(float v0, float v1, float v2, float v3) {
  int p = __builtin_amdgcn_cvt_pk_fp8_f32(v0, v1, 0, false);
  p = __builtin_amdgcn_cvt_pk_fp8_f32(v2, v3, p, true);
  return p;  // bytes [v0,v1,v2,v3]
}

// ---------------- weight cast + transpose: w[K][N] f32 -> wt[N][K] fp8 (x64) ----------------
__global__ void transpose_cast(const float* __restrict__ w, u8* __restrict__ wt,
                               int K, int N) {
  __shared__ float tile[32][33];
  int n0 = blockIdx.x * 32, k0 = blockIdx.y * 32;
  int tx = threadIdx.x, ty = threadIdx.y;   // block (32,8)
  #pragma unroll
  for (int i = 0; i < 32; i += 8)
    tile[ty + i][tx] = w[(size_t)(k0 + ty + i) * N + n0 + tx];
  __syncthreads();
  #pragma unroll
  for (int i = 0; i < 32; i += 8)
    wt[(size_t)(n0 + ty + i) * K + k0 + tx] = to_fp8(tile[tx][ty + i] * WSCALE);
}

// ---------------- LayerNorm (768) + cast to fp8 ----------------
__global__ __launch_bounds__(256)
void ln_cast_kernel(const float* __restrict__ x, const float* __restrict__ g,
                    const float* __restrict__ bta, u8* __restrict__ y) {
  int row = blockIdx.x;
  int tid = threadIdx.x;
  const float* xr = x + (size_t)row * C_;
  float v0 = xr[tid], v1 = xr[tid + 256], v2 = xr[tid + 512];
  float s  = v0 + v1 + v2;
  float sq = v0 * v0 + v1 * v1 + v2 * v2;
  #pragma unroll
  for (int off = 32; off > 0; off >>= 1) {
    s  += __shfl_xor(s,  off);
    sq += __shfl_xor(sq, off);
  }
  __shared__ float red[8];
  int wave = tid >> 6, lane = tid & 63;
  if (lane == 0) { red[wave] = s; red[4 + wave] = sq; }
  __syncthreads();
  s  = red[0] + red[1] + red[2] + red[3];
  sq = red[4] + red[5] + red[6] + red[7];
  float mean = s * (1.0f / C_);
  float var  = sq * (1.0f / C_) - mean * mean;
  float rstd = rsqrtf(var + 1e-5f);
  u8* yr = y + (size_t)row * C_;
  yr[tid]       = to_fp8((v0 - mean) * rstd * g[tid]       + bta[tid]);
  yr[tid + 256] = to_fp8((v1 - mean) * rstd * g[tid + 256] + bta[tid + 256]);
  yr[tid + 512] = to_fp8((v2 - mean) * rstd * g[tid + 512] + bta[tid + 512]);
}

// ---------------- fp8 GEMM: C[M,N] = A[M,K] @ Bt[N,K]^T, fp32 acc, result x(1/64) ----------
// EPI: 0 = store bf16 (qkv) | 1 = resid + (acc+bias)*ls, f32 (proj)
//      2 = gelu(acc+bias) fp8 (fc1) | 3 = resid + (acc+bias)*ls, f32 (fc2 -> d_out)
// LDS granule swizzle: physical 16B-granule p of row r holds logical granule p ^ ((r>>1)&3)
// (applied at the gll16 *source*; dest stays lane-contiguous). frag b64 reads then 2-way = free.
template <int EPI>
__global__ __launch_bounds__(256)
void gemm_bt(const u8* __restrict__ A, const u8* __restrict__ Bt,
             void* __restrict__ outp, const float* __restrict__ bias,
             const float* __restrict__ ls, const float* __restrict__ resid,
             int M, int N, int K) {
  constexpr int BM = 128, BN = 128, BK = 64;
  __shared__ __align__(16) u8 As[BM * BK];  // 8 KB
  __shared__ __align__(16) u8 Bs[BN * BK];  // 8 KB
  int tid  = threadIdx.x;
  int lane = tid & 63, wave = tid >> 6;
  int quad = lane >> 4, l16 = lane & 15;
  int m0 = blockIdx.y * BM, n0 = blockIdx.x * BN;
  int wm = (wave >> 1) * 64, wn = (wave & 1) * 64;

  // staging source pointers, granule-swizzled
  const u8* ag[2]; const u8* bg[2];
  #pragma unroll
  for (int s = 0; s < 2; s++) {
    int u = tid + s * 256;
    int r = u >> 2, g = (u & 3) ^ ((r >> 1) & 3);
    ag[s] = A  + (size_t)(m0 + r) * K + g * 16;
    bg[s] = Bt + (size_t)(n0 + r) * K + g * 16;
  }
  int swz = (l16 >> 1) & 3;

  const f32x4 fz = {0.f, 0.f, 0.f, 0.f};
  f32x4 acc[4][4];
  #pragma unroll
  for (int i = 0; i < 4; i++)
    #pragma unroll
    for (int j = 0; j < 4; j++) acc[i][j] = fz;

  for (int k0 = 0; k0 < K; k0 += BK) {
    gll16(ag[0] + k0, As + tid * 16);
    gll16(ag[1] + k0, As + 4096 + tid * 16);
    gll16(bg[0] + k0, Bs + tid * 16);
    gll16(bg[1] + k0, Bs + 4096 + tid * 16);
    __syncthreads();
    long af[4][2], bfr[4][2];
    #pragma unroll
    for (int i = 0; i < 4; i++)
      #pragma unroll
      for (int kk = 0; kk < 2; kk++)
        af[i][kk] = *(const long*)(As + (wm + i * 16 + l16) * 64
                                   + (((kk << 1) | (quad >> 1)) ^ swz) * 16 + (quad & 1) * 8);
    #pragma unroll
    for (int j = 0; j < 4; j++)
      #pragma unroll
      for (int kk = 0; kk < 2; kk++)
        bfr[j][kk] = *(const long*)(Bs + (wn + j * 16 + l16) * 64
                                    + (((kk << 1) | (quad >> 1)) ^ swz) * 16 + (quad & 1) * 8);
    #pragma unroll
    for (int kk = 0; kk < 2; kk++)
      #pragma unroll
      for (int i = 0; i < 4; i++)
        #pragma unroll
        for (int j = 0; j < 4; j++)
          acc[i][j] = __builtin_amdgcn_mfma_f32_16x16x32_fp8_fp8(af[i][kk], bfr[j][kk],
                                                                 acc[i][j], 0, 0, 0);
    __syncthreads();
  }

  // epilogue: D[row][col], row = quad*4 + r, col = l16 (per 16x16 frag); undo weight scale
  #pragma unroll
  for (int i = 0; i < 4; i++) {
    int rowb = m0 + wm + i * 16 + quad * 4;
    #pragma unroll
    for (int j = 0; j < 4; j++) {
      int col = n0 + wn + j * 16 + l16;
      #pragma unroll
      for (int r = 0; r < 4; r++) {
        float v = acc[i][j][r] * WINV;
        size_t idx = (size_t)(rowb + r) * N + col;
        if constexpr (EPI == 0) {
          ((bf16*)outp)[idx] = (bf16)v;
        } else if constexpr (EPI == 1) {
          ((float*)outp)[idx] = resid[idx] + (v + bias[col]) * ls[col];
        } else if constexpr (EPI == 2) {
          float t = v + bias[col];
          ((u8*)outp)[idx] = to_fp8(0.5f * t * (1.0f + erff(t * 0.70710678118f)));
        } else {
          ((float*)outp)[idx] = resid[idx] + (v + bias[col]) * ls[col];
        }
      }
    }
  }
}

// ---------------- V transpose: qkv[.,1536+h*64+d] bf16 -> vt[bh][d][n] f16 ----------------
__global__ void transpose_v(const bf16* __restrict__ qkv, f16* __restrict__ vt) {
  __shared__ bf16 tile[32][33];
  int bh = blockIdx.z;
  int b = bh / H_, h = bh % H_;
  int n0 = blockIdx.x * 32, d0 = blockIdx.y * 32;
  int tx = threadIdx.x, ty = threadIdx.y;   // block (32,8)
  const bf16* src = qkv + (size_t)(b * N_) * QKVN + 2 * C_ + h * HD_;
  #pragma unroll
  for (int i = 0; i < 32; i += 8)
    tile[ty + i][tx] = src[(size_t)(n0 + ty + i) * QKVN + d0 + tx];
  __syncthreads();
  f16* dst = vt + (size_t)bh * HD_ * N_;
  #pragma unroll
  for (int i = 0; i < 32; i += 8)
    dst[(size_t)(d0 + ty + i) * N_ + n0 + tx] = (f16)(float)tile[tx][ty + i];
}

// ---------------- flash attention, S^T formulation (bf16 internal, fp8 out) ----------------
__global__ __launch_bounds__(256)
void attn_kernel(const bf16* __restrict__ qkv, const f16* __restrict__ vt,
                 u8* __restrict__ o) {
  constexpr int KSTR = 72;    // K tile stride (64 + 8 pad), bf16
  constexpr int VSTR = 136;   // V^T tile stride (128 + 8 pad), f16
  __shared__ __align__(16) bf16 Ks[128 * KSTR];   // 18432 B
  __shared__ __align__(16) f16  Vs[HD_ * VSTR];   // 17408 B

  int tid = threadIdx.x, lane = tid & 63, wave = tid >> 6;
  int quad = lane >> 4, l16 = lane & 15;
  int bh = blockIdx.y;
  int b = bh / H_, h = bh % H_;
  int q0 = blockIdx.x * 128;
  const float CEXP = 0.125f * 1.44269504f;   // scale * log2(e)

  bf16x8 qf[2][2];
  #pragma unroll
  for (int i = 0; i < 2; i++)
    #pragma unroll
    for (int kk = 0; kk < 2; kk++)
      qf[i][kk] = *(const bf16x8*)(qkv + (size_t)(b * N_ + q0 + wave * 32 + i * 16 + l16) * QKVN
                                   + h * HD_ + kk * 32 + quad * 8);

  const f32x4 fz = {0.f, 0.f, 0.f, 0.f};
  f32x4 oacc[2][4];            // O^T[d = quad*4+r][q = l16]
  float m_run[2], l_run[2];
  #pragma unroll
  for (int i = 0; i < 2; i++) {
    #pragma unroll
    for (int jd = 0; jd < 4; jd++) oacc[i][jd] = fz;
    m_run[i] = -1e30f; l_run[i] = 0.f;
  }

  const bf16* kbase = qkv + (size_t)(b * N_) * QKVN + C_ + h * HD_;
  const f16*  vbase = vt + (size_t)bh * HD_ * N_;

  for (int kv = 0; kv < N_; kv += 128) {
    __syncthreads();
    #pragma unroll
    for (int u = 0; u < 4; u++) {
      int L = tid + u * 256;
      int r = L >> 3, c = (L & 7) * 8;
      *(bf16x8*)(Ks + r * KSTR + c) =
          *(const bf16x8*)(kbase + (size_t)(kv + r) * QKVN + c);
    }
    #pragma unroll
    for (int u = 0; u < 4; u++) {
      int L = tid + u * 256;
      int r = L >> 4, c = (L & 15) * 8;
      *(f16x8*)(Vs + r * VSTR + c) =
          *(const f16x8*)(vbase + (size_t)r * N_ + kv + c);
    }
    __syncthreads();

    // S^T = K @ Q^T
    f32x4 sv[2][8];
    #pragma unroll
    for (int i = 0; i < 2; i++)
      #pragma unroll
      for (int kf = 0; kf < 8; kf++) sv[i][kf] = fz;
    #pragma unroll
    for (int kk = 0; kk < 2; kk++) {
      #pragma unroll
      for (int kf = 0; kf < 8; kf++) {
        bf16x8 kb = *(const bf16x8*)(Ks + (kf * 16 + l16) * KSTR + kk * 32 + quad * 8);
        sv[0][kf] = __builtin_amdgcn_mfma_f32_16x16x32_bf16(kb, qf[0][kk], sv[0][kf], 0, 0, 0);
        sv[1][kf] = __builtin_amdgcn_mfma_f32_16x16x32_bf16(kb, qf[1][kk], sv[1][kf], 0, 0, 0);
      }
    }

    // online softmax: keys in regs, queries on l16
    f16x4 pb[2][8];
    #pragma unroll
    for (int i = 0; i < 2; i++) {
      float mx = sv[i][0][0];
      #pragma unroll
      for (int kf = 0; kf < 8; kf++)
        #pragma unroll
        for (int r = 0; r < 4; r++) mx = fmaxf(mx, sv[i][kf][r]);
      mx = fmaxf(mx, __shfl_xor(mx, 16));
      mx = fmaxf(mx, __shfl_xor(mx, 32));
      float mold = m_run[i];
      float mnew = fmaxf(mold, mx);
      float mb   = mnew * CEXP;
      float al   = exp2f(mold * CEXP - mb);
      float rs = 0.f;
      #pragma unroll
      for (int kf = 0; kf < 8; kf++) {
        #pragma unroll
        for (int r = 0; r < 4; r++) {
          float p = exp2f(sv[i][kf][r] * CEXP - mb);
          pb[i][kf][r] = (f16)p;
          rs += p;
        }
      }
      rs += __shfl_xor(rs, 16);
      rs += __shfl_xor(rs, 32);
      m_run[i] = mnew;
      l_run[i] = l_run[i] * al + rs;
      #pragma unroll
      for (int jd = 0; jd < 4; jd++) oacc[i][jd] *= al;
    }

    // O^T += V^T @ P^T
    #pragma unroll
    for (int kc = 0; kc < 8; kc++) {
      #pragma unroll
      for (int jd = 0; jd < 4; jd++) {
        f16x4 va = *(const f16x4*)(Vs + (jd * 16 + l16) * VSTR + kc * 16 + quad * 4);
        oacc[0][jd] = __builtin_amdgcn_mfma_f32_16x16x16f16(va, pb[0][kc], oacc[0][jd], 0, 0, 0);
        oacc[1][jd] = __builtin_amdgcn_mfma_f32_16x16x16f16(va, pb[1][kc], oacc[1][jd], 0, 0, 0);
      }
    }
  }

  // finalize: O = O^T / l, 4B packed fp8 stores
  #pragma unroll
  for (int i = 0; i < 2; i++) {
    float inv = 1.0f / l_run[i];
    int n = q0 + wave * 32 + i * 16 + l16;
    #pragma unroll
    for (int jd = 0; jd < 4; jd++) {
      int p = to_fp8x4(oacc[i][jd][0] * inv, oacc[i][jd][1] * inv,
                       oacc[i][jd][2] * inv, oacc[i][jd][3] * inv);
      *(int*)(o + (size_t)(b * N_ + n) * C_ + h * HD_ + jd * 16 + quad * 4) = p;
    }
  }
}

// ---------------- host: workspace layout + launch ----------------
#define WQKVT_OFF  0u
#define WPROJT_OFF 1769472u
#define WFC1T_OFF  2359296u
#define WFC2T_OFF  4718592u
#define Y_OFF      7077888u
#define QKV_OFF    19660800u    // bf16 qkv (75.5 MB); aliased by fp8 hbuf (50.3 MB) after attn
#define VT_OFF     95158272u
#define O_OFF      120324096u
#define X1_OFF     132907008u
#define WS_NEEDED  183238656u

extern "C" void kernel_launch(void* const* d_in, const int* in_sizes, int n_in,
                              void* d_out, int out_size, void* d_ws, size_t ws_size,
                              hipStream_t stream) {
  if (ws_size < (size_t)WS_NEEDED) return;

  const float* x      = (const float*)d_in[0];
  const float* w_qkv  = (const float*)d_in[1];
  const float* w_proj = (const float*)d_in[2];
  const float* b_proj = (const float*)d_in[3];
  const float* ln1_g  = (const float*)d_in[4];
  const float* ln1_b  = (const float*)d_in[5];
  const float* ln2_g  = (const float*)d_in[6];
  const float* ln2_b  = (const float*)d_in[7];
  const float* ls1_g  = (const float*)d_in[8];
  const float* ls2_g  = (const float*)d_in[9];
  const float* w_fc1  = (const float*)d_in[10];
  const float* b_fc1  = (const float*)d_in[11];
  const float* w_fc2  = (const float*)d_in[12];
  const float* b_fc2  = (const float*)d_in[13];

  char* ws = (char*)d_ws;
  u8*    wqkvT  = (u8*)(ws + WQKVT_OFF);
  u8*    wprojT = (u8*)(ws + WPROJT_OFF);
  u8*    wfc1T  = (u8*)(ws + WFC1T_OFF);
  u8*    wfc2T  = (u8*)(ws + WFC2T_OFF);
  u8*    y      = (u8*)(ws + Y_OFF);
  bf16*  qkv    = (bf16*)(ws + QKV_OFF);
  u8*    hbuf   = (u8*)(ws + QKV_OFF);   // alias: qkv dead after attention
  f16*   vt     = (f16*)(ws + VT_OFF);
  u8*    o      = (u8*)(ws + O_OFF);
  float* x1     = (float*)(ws + X1_OFF);
  float* out    = (float*)d_out;

  dim3 tb(32, 8);
  transpose_cast<<<dim3(QKVN / 32, C_ / 32), tb, 0, stream>>>(w_qkv,  wqkvT,  C_,   QKVN);
  transpose_cast<<<dim3(C_   / 32, C_ / 32), tb, 0, stream>>>(w_proj, wprojT, C_,   C_);
  transpose_cast<<<dim3(MLP_ / 32, C_ / 32), tb, 0, stream>>>(w_fc1,  wfc1T,  C_,   MLP_);
  transpose_cast<<<dim3(C_ / 32, MLP_ / 32), tb, 0, stream>>>(w_fc2,  wfc2T,  MLP_, C_);

  ln_cast_kernel<<<M_, 256, 0, stream>>>(x, ln1_g, ln1_b, y);

  gemm_bt<0><<<dim3(QKVN / 128, M_ / 128), 256, 0, stream>>>(
      y, wqkvT, qkv, nullptr, nullptr, nullptr, M_, QKVN, C_);

  transpose_v<<<dim3(N_ / 32, HD_ / 32, B_ * H_), tb, 0, stream>>>(qkv, vt);

  attn_kernel<<<dim3(N_ / 128, B_ * H_), 256, 0, stream>>>(qkv, vt, o);

  gemm_bt<1><<<dim3(C_ / 128, M_ / 128), 256, 0, stream>>>(
      o, wprojT, x1, b_proj, ls1_g, x, M_, C_, C_);

  ln_cast_kernel<<<M_, 256, 0, stream>>>(x1, ln2_g, ln2_b, y);

  gemm_bt<2><<<dim3(MLP_ / 128, M_ / 128), 256, 0, stream>>>(
      y, wfc1T, hbuf, b_fc1, nullptr, nullptr, M_, MLP_, C_);

  gemm_bt<3><<<dim3(C_ / 128, M_ / 128), 256, 0, stream>>>(
      hbuf, wfc2T, out, b_fc2, ls2_g, x1, M_, C_, MLP_);
}

// Round 4
// 603.528 us; speedup vs baseline: 1.3065x; 1.0237x over previous
//
#include <hip/hip_runtime.h>
#include <cstdint>
#include <cstddef>

// ---------------- types ----------------
typedef __bf16 bf16;
typedef __bf16 bf16x4 __attribute__((ext_vector_type(4)));
typedef __bf16 bf16x8 __attribute__((ext_vector_type(8)));
typedef _Float16 f16;
typedef _Float16 f16x4 __attribute__((ext_vector_type(4)));
typedef _Float16 f16x8 __attribute__((ext_vector_type(8)));
typedef float  f32x4  __attribute__((ext_vector_type(4)));
typedef unsigned char u8;

#define B_   16
#define N_   1024
#define C_   768
#define H_   12
#define HD_  64
#define M_   (B_*N_)      // 16384 rows
#define MLP_ 3072
#define QKVN 2304         // 3*C
#define WSCALE 64.0f      // weights cast to fp8 at x64 (0.02-scale weights are subnormal in e4m3)
#define WINV  (1.0f/64.0f)

__device__ __forceinline__ void gll16(const void* g, void* l) {
  __builtin_amdgcn_global_load_lds((const __attribute__((address_space(1))) void*)g,
                                   (__attribute__((address_space(3))) void*)l,
                                   16, 0, 0);
}

// native v_exp_f32 (exp2); libm exp2f lowers to slow OCML path
__device__ __forceinline__ float fast_exp2(float x) {
  return __builtin_amdgcn_exp2f(x);
}

// fp8 e4m3 (OCP on gfx950) converts via HW packed cvt
__device__ __forceinline__ u8 to_fp8(float a) {
  return (u8)(__builtin_amdgcn_cvt_pk_fp8_f32(a, a, 0, false) & 0xff);
}
__device__ __forceinline__ int to_fp8x4(float v0, float v1, float v2, float v3) {
  int p = __builtin_amdgcn_cvt_pk_fp8_f32(v0, v1, 0, false);
  p = __builtin_amdgcn_cvt_pk_fp8_f32(v2, v3, p, true);
  return p;  // bytes [v0,v1,v2,v3]
}

// tanh-form GELU via native exp2: t*sigmoid(2*sqrt(2/pi)*(t+0.044715 t^3))
// max dev from erf-GELU ~1e-3; suppressed by fc2 weights * ls2=1e-5 downstream.
__device__ __forceinline__ float fast_gelu(float t) {
  float z = 2.30220568f * (t + 0.044715f * t * t * t);  // 2*log2(e)*sqrt(2/pi)*(...)
  return t / (1.0f + fast_exp2(-z));
}

// ---------------- weight cast + transpose: w[K][N] f32 -> wt[N][K] fp8 (x64) ----------------
__global__ void transpose_cast(const float* __restrict__ w, u8* __restrict__ wt,
                               int K, int N) {
  __shared__ float tile[32][33];
  int n0 = blockIdx.x * 32, k0 = blockIdx.y * 32;
  int tx = threadIdx.x, ty = threadIdx.y;   // block (32,8)
  #pragma unroll
  for (int i = 0; i < 32; i += 8)
    tile[ty + i][tx] = w[(size_t)(k0 + ty + i) * N + n0 + tx];
  __syncthreads();
  #pragma unroll
  for (int i = 0; i < 32; i += 8)
    wt[(size_t)(n0 + ty + i) * K + k0 + tx] = to_fp8(tile[tx][ty + i] * WSCALE);
}

// ---------------- LayerNorm (768) + cast to fp8 ----------------
__global__ __launch_bounds__(256)
void ln_cast_kernel(const float* __restrict__ x, const float* __restrict__ g,
                    const float* __restrict__ bta, u8* __restrict__ y) {
  int row = blockIdx.x;
  int tid = threadIdx.x;
  const float* xr = x + (size_t)row * C_;
  float v0 = xr[tid], v1 = xr[tid + 256], v2 = xr[tid + 512];
  float s  = v0 + v1 + v2;
  float sq = v0 * v0 + v1 * v1 + v2 * v2;
  #pragma unroll
  for (int off = 32; off > 0; off >>= 1) {
    s  += __shfl_xor(s,  off);
    sq += __shfl_xor(sq, off);
  }
  __shared__ float red[8];
  int wave = tid >> 6, lane = tid & 63;
  if (lane == 0) { red[wave] = s; red[4 + wave] = sq; }
  __syncthreads();
  s  = red[0] + red[1] + red[2] + red[3];
  sq = red[4] + red[5] + red[6] + red[7];
  float mean = s * (1.0f / C_);
  float var  = sq * (1.0f / C_) - mean * mean;
  float rstd = rsqrtf(var + 1e-5f);
  u8* yr = y + (size_t)row * C_;
  yr[tid]       = to_fp8((v0 - mean) * rstd * g[tid]       + bta[tid]);
  yr[tid + 256] = to_fp8((v1 - mean) * rstd * g[tid + 256] + bta[tid + 256]);
  yr[tid + 512] = to_fp8((v2 - mean) * rstd * g[tid + 512] + bta[tid + 512]);
}

// ---------------- fp8 GEMM: C[M,N] = A[M,K] @ Bt[N,K]^T, fp32 acc, result x(1/64) ----------
// EPI: 0 = store bf16 (qkv) | 1 = resid + (acc+bias)*ls, f32 (proj)
//      2 = gelu(acc+bias) fp8 (fc1) | 3 = resid + (acc+bias)*ls, f32 (fc2 -> d_out)
template <int EPI>
__global__ __launch_bounds__(256)
void gemm_bt(const u8* __restrict__ A, const u8* __restrict__ Bt,
             void* __restrict__ outp, const float* __restrict__ bias,
             const float* __restrict__ ls, const float* __restrict__ resid,
             int M, int N, int K) {
  constexpr int BM = 128, BN = 128, BK = 64;
  __shared__ __align__(16) u8 As[BM * BK];  // 8 KB
  __shared__ __align__(16) u8 Bs[BN * BK];  // 8 KB
  int tid  = threadIdx.x;
  int lane = tid & 63, wave = tid >> 6;
  int quad = lane >> 4, l16 = lane & 15;
  int m0 = blockIdx.y * BM, n0 = blockIdx.x * BN;
  int wm = (wave >> 1) * 64, wn = (wave & 1) * 64;

  // staging source pointers, granule-swizzled
  const u8* ag[2]; const u8* bg[2];
  #pragma unroll
  for (int s = 0; s < 2; s++) {
    int u = tid + s * 256;
    int r = u >> 2, g = (u & 3) ^ ((r >> 1) & 3);
    ag[s] = A  + (size_t)(m0 + r) * K + g * 16;
    bg[s] = Bt + (size_t)(n0 + r) * K + g * 16;
  }
  int swz = (l16 >> 1) & 3;

  const f32x4 fz = {0.f, 0.f, 0.f, 0.f};
  f32x4 acc[4][4];
  #pragma unroll
  for (int i = 0; i < 4; i++)
    #pragma unroll
    for (int j = 0; j < 4; j++) acc[i][j] = fz;

  for (int k0 = 0; k0 < K; k0 += BK) {
    gll16(ag[0] + k0, As + tid * 16);
    gll16(ag[1] + k0, As + 4096 + tid * 16);
    gll16(bg[0] + k0, Bs + tid * 16);
    gll16(bg[1] + k0, Bs + 4096 + tid * 16);
    __syncthreads();
    long af[4][2], bfr[4][2];
    #pragma unroll
    for (int i = 0; i < 4; i++)
      #pragma unroll
      for (int kk = 0; kk < 2; kk++)
        af[i][kk] = *(const long*)(As + (wm + i * 16 + l16) * 64
                                   + (((kk << 1) | (quad >> 1)) ^ swz) * 16 + (quad & 1) * 8);
    #pragma unroll
    for (int j = 0; j < 4; j++)
      #pragma unroll
      for (int kk = 0; kk < 2; kk++)
        bfr[j][kk] = *(const long*)(Bs + (wn + j * 16 + l16) * 64
                                    + (((kk << 1) | (quad >> 1)) ^ swz) * 16 + (quad & 1) * 8);
    #pragma unroll
    for (int kk = 0; kk < 2; kk++)
      #pragma unroll
      for (int i = 0; i < 4; i++)
        #pragma unroll
        for (int j = 0; j < 4; j++)
          acc[i][j] = __builtin_amdgcn_mfma_f32_16x16x32_fp8_fp8(af[i][kk], bfr[j][kk],
                                                                 acc[i][j], 0, 0, 0);
    __syncthreads();
  }

  // epilogue: D[row][col], row = quad*4 + r, col = l16 (per 16x16 frag); undo weight scale
  #pragma unroll
  for (int i = 0; i < 4; i++) {
    int rowb = m0 + wm + i * 16 + quad * 4;
    #pragma unroll
    for (int j = 0; j < 4; j++) {
      int col = n0 + wn + j * 16 + l16;
      #pragma unroll
      for (int r = 0; r < 4; r++) {
        float v = acc[i][j][r] * WINV;
        size_t idx = (size_t)(rowb + r) * N + col;
        if constexpr (EPI == 0) {
          ((bf16*)outp)[idx] = (bf16)v;
        } else if constexpr (EPI == 1) {
          ((float*)outp)[idx] = resid[idx] + (v + bias[col]) * ls[col];
        } else if constexpr (EPI == 2) {
          ((u8*)outp)[idx] = to_fp8(fast_gelu(v + bias[col]));
        } else {
          ((float*)outp)[idx] = resid[idx] + (v + bias[col]) * ls[col];
        }
      }
    }
  }
}

// ---------------- V transpose: qkv[.,1536+h*64+d] bf16 -> vt[bh][d][n] f16 ----------------
__global__ void transpose_v(const bf16* __restrict__ qkv, f16* __restrict__ vt) {
  __shared__ bf16 tile[32][33];
  int bh = blockIdx.z;
  int b = bh / H_, h = bh % H_;
  int n0 = blockIdx.x * 32, d0 = blockIdx.y * 32;
  int tx = threadIdx.x, ty = threadIdx.y;   // block (32,8)
  const bf16* src = qkv + (size_t)(b * N_) * QKVN + 2 * C_ + h * HD_;
  #pragma unroll
  for (int i = 0; i < 32; i += 8)
    tile[ty + i][tx] = src[(size_t)(n0 + ty + i) * QKVN + d0 + tx];
  __syncthreads();
  f16* dst = vt + (size_t)bh * HD_ * N_;
  #pragma unroll
  for (int i = 0; i < 32; i += 8)
    dst[(size_t)(d0 + ty + i) * N_ + n0 + tx] = (f16)(float)tile[tx][ty + i];
}

// ---------------- flash attention, S^T formulation (bf16 internal, fp8 out) ----------------
__global__ __launch_bounds__(256)
void attn_kernel(const bf16* __restrict__ qkv, const f16* __restrict__ vt,
                 u8* __restrict__ o) {
  constexpr int KSTR = 72;    // K tile stride (64 + 8 pad), bf16
  constexpr int VSTR = 136;   // V^T tile stride (128 + 8 pad), f16
  __shared__ __align__(16) bf16 Ks[128 * KSTR];   // 18432 B
  __shared__ __align__(16) f16  Vs[HD_ * VSTR];   // 17408 B

  int tid = threadIdx.x, lane = tid & 63, wave = tid >> 6;
  int quad = lane >> 4, l16 = lane & 15;
  int bh = blockIdx.y;
  int b = bh / H_, h = bh % H_;
  int q0 = blockIdx.x * 128;
  const float CEXP = 0.125f * 1.44269504f;   // scale * log2(e)

  bf16x8 qf[2][2];
  #pragma unroll
  for (int i = 0; i < 2; i++)
    #pragma unroll
    for (int kk = 0; kk < 2; kk++)
      qf[i][kk] = *(const bf16x8*)(qkv + (size_t)(b * N_ + q0 + wave * 32 + i * 16 + l16) * QKVN
                                   + h * HD_ + kk * 32 + quad * 8);

  const f32x4 fz = {0.f, 0.f, 0.f, 0.f};
  f32x4 oacc[2][4];            // O^T[d = quad*4+r][q = l16]
  float m_run[2], l_run[2];
  #pragma unroll
  for (int i = 0; i < 2; i++) {
    #pragma unroll
    for (int jd = 0; jd < 4; jd++) oacc[i][jd] = fz;
    m_run[i] = -1e30f; l_run[i] = 0.f;
  }

  const bf16* kbase = qkv + (size_t)(b * N_) * QKVN + C_ + h * HD_;
  const f16*  vbase = vt + (size_t)bh * HD_ * N_;

  for (int kv = 0; kv < N_; kv += 128) {
    __syncthreads();
    #pragma unroll
    for (int u = 0; u < 4; u++) {
      int L = tid + u * 256;
      int r = L >> 3, c = (L & 7) * 8;
      *(bf16x8*)(Ks + r * KSTR + c) =
          *(const bf16x8*)(kbase + (size_t)(kv + r) * QKVN + c);
    }
    #pragma unroll
    for (int u = 0; u < 4; u++) {
      int L = tid + u * 256;
      int r = L >> 4, c = (L & 15) * 8;
      *(f16x8*)(Vs + r * VSTR + c) =
          *(const f16x8*)(vbase + (size_t)r * N_ + kv + c);
    }
    __syncthreads();

    // S^T = K @ Q^T
    f32x4 sv[2][8];
    #pragma unroll
    for (int i = 0; i < 2; i++)
      #pragma unroll
      for (int kf = 0; kf < 8; kf++) sv[i][kf] = fz;
    #pragma unroll
    for (int kk = 0; kk < 2; kk++) {
      #pragma unroll
      for (int kf = 0; kf < 8; kf++) {
        bf16x8 kb = *(const bf16x8*)(Ks + (kf * 16 + l16) * KSTR + kk * 32 + quad * 8);
        sv[0][kf] = __builtin_amdgcn_mfma_f32_16x16x32_bf16(kb, qf[0][kk], sv[0][kf], 0, 0, 0);
        sv[1][kf] = __builtin_amdgcn_mfma_f32_16x16x32_bf16(kb, qf[1][kk], sv[1][kf], 0, 0, 0);
      }
    }

    // online softmax: keys in regs, queries on l16; native v_exp_f32 throughout
    f16x4 pb[2][8];
    #pragma unroll
    for (int i = 0; i < 2; i++) {
      float mx = sv[i][0][0];
      #pragma unroll
      for (int kf = 0; kf < 8; kf++)
        #pragma unroll
        for (int r = 0; r < 4; r++) mx = fmaxf(mx, sv[i][kf][r]);
      mx = fmaxf(mx, __shfl_xor(mx, 16));
      mx = fmaxf(mx, __shfl_xor(mx, 32));
      float mold = m_run[i];
      float mnew = fmaxf(mold, mx);
      float mb   = mnew * CEXP;
      float al   = fast_exp2(mold * CEXP - mb);
      float rs = 0.f;
      #pragma unroll
      for (int kf = 0; kf < 8; kf++) {
        #pragma unroll
        for (int r = 0; r < 4; r++) {
          float p = fast_exp2(sv[i][kf][r] * CEXP - mb);
          pb[i][kf][r] = (f16)p;
          rs += p;
        }
      }
      rs += __shfl_xor(rs, 16);
      rs += __shfl_xor(rs, 32);
      m_run[i] = mnew;
      l_run[i] = l_run[i] * al + rs;
      #pragma unroll
      for (int jd = 0; jd < 4; jd++) oacc[i][jd] *= al;
    }

    // O^T += V^T @ P^T
    #pragma unroll
    for (int kc = 0; kc < 8; kc++) {
      #pragma unroll
      for (int jd = 0; jd < 4; jd++) {
        f16x4 va = *(const f16x4*)(Vs + (jd * 16 + l16) * VSTR + kc * 16 + quad * 4);
        oacc[0][jd] = __builtin_amdgcn_mfma_f32_16x16x16f16(va, pb[0][kc], oacc[0][jd], 0, 0, 0);
        oacc[1][jd] = __builtin_amdgcn_mfma_f32_16x16x16f16(va, pb[1][kc], oacc[1][jd], 0, 0, 0);
      }
    }
  }

  // finalize: O = O^T / l, 4B packed fp8 stores
  #pragma unroll
  for (int i = 0; i < 2; i++) {
    float inv = 1.0f / l_run[i];
    int n = q0 + wave * 32 + i * 16 + l16;
    #pragma unroll
    for (int jd = 0; jd < 4; jd++) {
      int p = to_fp8x4(oacc[i][jd][0] * inv, oacc[i][jd][1] * inv,
                       oacc[i][jd][2] * inv, oacc[i][jd][3] * inv);
      *(int*)(o + (size_t)(b * N_ + n) * C_ + h * HD_ + jd * 16 + quad * 4) = p;
    }
  }
}

// ---------------- host: workspace layout + launch ----------------
#define WQKVT_OFF  0u
#define WPROJT_OFF 1769472u
#define WFC1T_OFF  2359296u
#define WFC2T_OFF  4718592u
#define Y_OFF      7077888u
#define QKV_OFF    19660800u    // bf16 qkv (75.5 MB); aliased by fp8 hbuf (50.3 MB) after attn
#define VT_OFF     95158272u
#define O_OFF      120324096u
#define X1_OFF     132907008u
#define WS_NEEDED  183238656u

extern "C" void kernel_launch(void* const* d_in, const int* in_sizes, int n_in,
                              void* d_out, int out_size, void* d_ws, size_t ws_size,
                              hipStream_t stream) {
  if (ws_size < (size_t)WS_NEEDED) return;

  const float* x      = (const float*)d_in[0];
  const float* w_qkv  = (const float*)d_in[1];
  const float* w_proj = (const float*)d_in[2];
  const float* b_proj = (const float*)d_in[3];
  const float* ln1_g  = (const float*)d_in[4];
  const float* ln1_b  = (const float*)d_in[5];
  const float* ln2_g  = (const float*)d_in[6];
  const float* ln2_b  = (const float*)d_in[7];
  const float* ls1_g  = (const float*)d_in[8];
  const float* ls2_g  = (const float*)d_in[9];
  const float* w_fc1  = (const float*)d_in[10];
  const float* b_fc1  = (const float*)d_in[11];
  const float* w_fc2  = (const float*)d_in[12];
  const float* b_fc2  = (const float*)d_in[13];

  char* ws = (char*)d_ws;
  u8*    wqkvT  = (u8*)(ws + WQKVT_OFF);
  u8*    wprojT = (u8*)(ws + WPROJT_OFF);
  u8*    wfc1T  = (u8*)(ws + WFC1T_OFF);
  u8*    wfc2T  = (u8*)(ws + WFC2T_OFF);
  u8*    y      = (u8*)(ws + Y_OFF);
  bf16*  qkv    = (bf16*)(ws + QKV_OFF);
  u8*    hbuf   = (u8*)(ws + QKV_OFF);   // alias: qkv dead after attention
  f16*   vt     = (f16*)(ws + VT_OFF);
  u8*    o      = (u8*)(ws + O_OFF);
  float* x1     = (float*)(ws + X1_OFF);
  float* out    = (float*)d_out;

  dim3 tb(32, 8);
  transpose_cast<<<dim3(QKVN / 32, C_ / 32), tb, 0, stream>>>(w_qkv,  wqkvT,  C_,   QKVN);
  transpose_cast<<<dim3(C_   / 32, C_ / 32), tb, 0, stream>>>(w_proj, wprojT, C_,   C_);
  transpose_cast<<<dim3(MLP_ / 32, C_ / 32), tb, 0, stream>>>(w_fc1,  wfc1T,  C_,   MLP_);
  transpose_cast<<<dim3(C_ / 32, MLP_ / 32), tb, 0, stream>>>(w_fc2,  wfc2T,  MLP_, C_);

  ln_cast_kernel<<<M_, 256, 0, stream>>>(x, ln1_g, ln1_b, y);

  gemm_bt<0><<<dim3(QKVN / 128, M_ / 128), 256, 0, stream>>>(
      y, wqkvT, qkv, nullptr, nullptr, nullptr, M_, QKVN, C_);

  transpose_v<<<dim3(N_ / 32, HD_ / 32, B_ * H_), tb, 0, stream>>>(qkv, vt);

  attn_kernel<<<dim3(N_ / 128, B_ * H_), 256, 0, stream>>>(qkv, vt, o);

  gemm_bt<1><<<dim3(C_ / 128, M_ / 128), 256, 0, stream>>>(
      o, wprojT, x1, b_proj, ls1_g, x, M_, C_, C_);

  ln_cast_kernel<<<M_, 256, 0, stream>>>(x1, ln2_g, ln2_b, y);

  gemm_bt<2><<<dim3(MLP_ / 128, M_ / 128), 256, 0, stream>>>(
      y, wfc1T, hbuf, b_fc1, nullptr, nullptr, M_, MLP_, C_);

  gemm_bt<3><<<dim3(C_ / 128, M_ / 128), 256, 0, stream>>>(
      hbuf, wfc2T, out, b_fc2, ls2_g, x1, M_, C_, MLP_);
}

// Round 5
// 549.780 us; speedup vs baseline: 1.4342x; 1.0978x over previous
//
#include <hip/hip_runtime.h>
#include <cstdint>
#include <cstddef>

// ---------------- types ----------------
typedef __bf16 bf16;
typedef __bf16 bf16x4 __attribute__((ext_vector_type(4)));
typedef __bf16 bf16x8 __attribute__((ext_vector_type(8)));
typedef _Float16 f16;
typedef _Float16 f16x4 __attribute__((ext_vector_type(4)));
typedef _Float16 f16x8 __attribute__((ext_vector_type(8)));
typedef float  f32x4  __attribute__((ext_vector_type(4)));
typedef unsigned char u8;

#define B_   16
#define N_   1024
#define C_   768
#define H_   12
#define HD_  64
#define M_   (B_*N_)      // 16384 rows
#define MLP_ 3072
#define QKVN 2304         // 3*C
#define WSCALE 64.0f      // weights cast to fp8 at x64 (0.02-scale weights are subnormal in e4m3)
#define WINV  (1.0f/64.0f)

__device__ __forceinline__ void gll16(const void* g, void* l) {
  __builtin_amdgcn_global_load_lds((const __attribute__((address_space(1))) void*)g,
                                   (__attribute__((address_space(3))) void*)l,
                                   16, 0, 0);
}

// native v_exp_f32 (exp2); libm exp2f lowers to slow OCML path
__device__ __forceinline__ float fast_exp2(float x) {
  return __builtin_amdgcn_exp2f(x);
}

// fp8 e4m3 (OCP on gfx950) converts via HW packed cvt
__device__ __forceinline__ u8 to_fp8(float a) {
  return (u8)(__builtin_amdgcn_cvt_pk_fp8_f32(a, a, 0, false) & 0xff);
}
__device__ __forceinline__ int to_fp8x4(float v0, float v1, float v2, float v3) {
  int p = __builtin_amdgcn_cvt_pk_fp8_f32(v0, v1, 0, false);
  p = __builtin_amdgcn_cvt_pk_fp8_f32(v2, v3, p, true);
  return p;  // bytes [v0,v1,v2,v3]
}

// tanh-form GELU via native exp2
__device__ __forceinline__ float fast_gelu(float t) {
  float z = 2.30220568f * (t + 0.044715f * t * t * t);
  return t / (1.0f + fast_exp2(-z));
}

// ---------------- weight cast + transpose: w[K][N] f32 -> wt[N][K] fp8 (x64) ----------------
__global__ void transpose_cast(const float* __restrict__ w, u8* __restrict__ wt,
                               int K, int N) {
  __shared__ float tile[32][33];
  int n0 = blockIdx.x * 32, k0 = blockIdx.y * 32;
  int tx = threadIdx.x, ty = threadIdx.y;   // block (32,8)
  #pragma unroll
  for (int i = 0; i < 32; i += 8)
    tile[ty + i][tx] = w[(size_t)(k0 + ty + i) * N + n0 + tx];
  __syncthreads();
  #pragma unroll
  for (int i = 0; i < 32; i += 8)
    wt[(size_t)(n0 + ty + i) * K + k0 + tx] = to_fp8(tile[tx][ty + i] * WSCALE);
}

// ---------------- LayerNorm (768) + cast to fp8 ----------------
__global__ __launch_bounds__(256)
void ln_cast_kernel(const float* __restrict__ x, const float* __restrict__ g,
                    const float* __restrict__ bta, u8* __restrict__ y) {
  int row = blockIdx.x;
  int tid = threadIdx.x;
  const float* xr = x + (size_t)row * C_;
  float v0 = xr[tid], v1 = xr[tid + 256], v2 = xr[tid + 512];
  float s  = v0 + v1 + v2;
  float sq = v0 * v0 + v1 * v1 + v2 * v2;
  #pragma unroll
  for (int off = 32; off > 0; off >>= 1) {
    s  += __shfl_xor(s,  off);
    sq += __shfl_xor(sq, off);
  }
  __shared__ float red[8];
  int wave = tid >> 6, lane = tid & 63;
  if (lane == 0) { red[wave] = s; red[4 + wave] = sq; }
  __syncthreads();
  s  = red[0] + red[1] + red[2] + red[3];
  sq = red[4] + red[5] + red[6] + red[7];
  float mean = s * (1.0f / C_);
  float var  = sq * (1.0f / C_) - mean * mean;
  float rstd = rsqrtf(var + 1e-5f);
  u8* yr = y + (size_t)row * C_;
  yr[tid]       = to_fp8((v0 - mean) * rstd * g[tid]       + bta[tid]);
  yr[tid + 256] = to_fp8((v1 - mean) * rstd * g[tid + 256] + bta[tid + 256]);
  yr[tid + 512] = to_fp8((v2 - mean) * rstd * g[tid + 512] + bta[tid + 512]);
}

// ---------------- fp8 GEMM: C[M,N] = A[M,K] @ Bt[N,K]^T, fp32 acc, result x(1/64) ----------
// 1-D grid nb*128, XCD-aware remap: xcd=bid&7, m-tile = xcd + 8*(seq/nb), n-tile = seq%nb
// -> all n-tiles of an m-tile run consecutively on ONE XCD (A-tile hot in that L2);
//    B (weights, <=2.4MB fp8) fetched once per XCD.
template <int EPI>
__global__ __launch_bounds__(256)
void gemm_bt(const u8* __restrict__ A, const u8* __restrict__ Bt,
             void* __restrict__ outp, const float* __restrict__ bias,
             const float* __restrict__ ls, const float* __restrict__ resid,
             int M, int N, int K, int nb) {
  constexpr int BM = 128, BN = 128, BK = 64;
  __shared__ __align__(16) u8 As[BM * BK];  // 8 KB
  __shared__ __align__(16) u8 Bs[BN * BK];  // 8 KB
  int tid  = threadIdx.x;
  int lane = tid & 63, wave = tid >> 6;
  int quad = lane >> 4, l16 = lane & 15;
  int bid = blockIdx.x;
  int xcd = bid & 7, seq = bid >> 3;
  int mi = xcd + 8 * (seq / nb), ni = seq % nb;
  int m0 = mi * BM, n0 = ni * BN;
  int wm = (wave >> 1) * 64, wn = (wave & 1) * 64;

  // staging source pointers, granule-swizzled
  const u8* ag[2]; const u8* bg[2];
  #pragma unroll
  for (int s = 0; s < 2; s++) {
    int u = tid + s * 256;
    int r = u >> 2, g = (u & 3) ^ ((r >> 1) & 3);
    ag[s] = A  + (size_t)(m0 + r) * K + g * 16;
    bg[s] = Bt + (size_t)(n0 + r) * K + g * 16;
  }
  int swz = (l16 >> 1) & 3;

  const f32x4 fz = {0.f, 0.f, 0.f, 0.f};
  f32x4 acc[4][4];
  #pragma unroll
  for (int i = 0; i < 4; i++)
    #pragma unroll
    for (int j = 0; j < 4; j++) acc[i][j] = fz;

  for (int k0 = 0; k0 < K; k0 += BK) {
    gll16(ag[0] + k0, As + tid * 16);
    gll16(ag[1] + k0, As + 4096 + tid * 16);
    gll16(bg[0] + k0, Bs + tid * 16);
    gll16(bg[1] + k0, Bs + 4096 + tid * 16);
    __syncthreads();
    long af[4][2], bfr[4][2];
    #pragma unroll
    for (int i = 0; i < 4; i++)
      #pragma unroll
      for (int kk = 0; kk < 2; kk++)
        af[i][kk] = *(const long*)(As + (wm + i * 16 + l16) * 64
                                   + (((kk << 1) | (quad >> 1)) ^ swz) * 16 + (quad & 1) * 8);
    #pragma unroll
    for (int j = 0; j < 4; j++)
      #pragma unroll
      for (int kk = 0; kk < 2; kk++)
        bfr[j][kk] = *(const long*)(Bs + (wn + j * 16 + l16) * 64
                                    + (((kk << 1) | (quad >> 1)) ^ swz) * 16 + (quad & 1) * 8);
    #pragma unroll
    for (int kk = 0; kk < 2; kk++)
      #pragma unroll
      for (int i = 0; i < 4; i++)
        #pragma unroll
        for (int j = 0; j < 4; j++)
          acc[i][j] = __builtin_amdgcn_mfma_f32_16x16x32_fp8_fp8(af[i][kk], bfr[j][kk],
                                                                 acc[i][j], 0, 0, 0);
    __syncthreads();
  }

  #pragma unroll
  for (int i = 0; i < 4; i++) {
    int rowb = m0 + wm + i * 16 + quad * 4;
    #pragma unroll
    for (int j = 0; j < 4; j++) {
      int col = n0 + wn + j * 16 + l16;
      #pragma unroll
      for (int r = 0; r < 4; r++) {
        float v = acc[i][j][r] * WINV;
        size_t idx = (size_t)(rowb + r) * N + col;
        if constexpr (EPI == 0) {
          ((bf16*)outp)[idx] = (bf16)v;
        } else if constexpr (EPI == 1) {
          ((float*)outp)[idx] = resid[idx] + (v + bias[col]) * ls[col];
        } else if constexpr (EPI == 2) {
          ((u8*)outp)[idx] = to_fp8(fast_gelu(v + bias[col]));
        } else {
          ((float*)outp)[idx] = resid[idx] + (v + bias[col]) * ls[col];
        }
      }
    }
  }
}

// ---------------- V transpose: qkv[.,1536+h*64+d] bf16 -> vt[bh][d][n] f16 ----------------
__global__ void transpose_v(const bf16* __restrict__ qkv, f16* __restrict__ vt) {
  __shared__ bf16 tile[32][33];
  int bh = blockIdx.z;
  int b = bh / H_, h = bh % H_;
  int n0 = blockIdx.x * 32, d0 = blockIdx.y * 32;
  int tx = threadIdx.x, ty = threadIdx.y;   // block (32,8)
  const bf16* src = qkv + (size_t)(b * N_) * QKVN + 2 * C_ + h * HD_;
  #pragma unroll
  for (int i = 0; i < 32; i += 8)
    tile[ty + i][tx] = src[(size_t)(n0 + ty + i) * QKVN + d0 + tx];
  __syncthreads();
  f16* dst = vt + (size_t)bh * HD_ * N_;
  #pragma unroll
  for (int i = 0; i < 32; i += 8)
    dst[(size_t)(d0 + ty + i) * N_ + n0 + tx] = (f16)(float)tile[tx][ty + i];
}

// ---------------- flash attention, S^T formulation ----------------
// 1-D grid 1536, XCD remap: bh = (bid&7) + 8*(seq>>3), q-tile = seq&7
// -> all 8 q-tiles of one bh co-resident on one XCD; K/V L2-hit after first touch.
// Register prefetch: next K/V tile loaded into VGPRs during compute.
__global__ __launch_bounds__(256)
void attn_kernel(const bf16* __restrict__ qkv, const f16* __restrict__ vt,
                 u8* __restrict__ o) {
  constexpr int KSTR = 72;    // K tile stride (64 + 8 pad), bf16
  constexpr int VSTR = 136;   // V^T tile stride (128 + 8 pad), f16
  __shared__ __align__(16) bf16 Ks[128 * KSTR];   // 18432 B
  __shared__ __align__(16) f16  Vs[HD_ * VSTR];   // 17408 B

  int tid = threadIdx.x, lane = tid & 63, wave = tid >> 6;
  int quad = lane >> 4, l16 = lane & 15;
  int bid = blockIdx.x;
  int xcd = bid & 7, seq = bid >> 3;
  int bh = xcd + 8 * (seq >> 3);
  int b = bh / H_, h = bh % H_;
  int q0 = (seq & 7) * 128;
  const float CEXP = 0.125f * 1.44269504f;   // scale * log2(e)

  bf16x8 qf[2][2];
  #pragma unroll
  for (int i = 0; i < 2; i++)
    #pragma unroll
    for (int kk = 0; kk < 2; kk++)
      qf[i][kk] = *(const bf16x8*)(qkv + (size_t)(b * N_ + q0 + wave * 32 + i * 16 + l16) * QKVN
                                   + h * HD_ + kk * 32 + quad * 8);

  const f32x4 fz = {0.f, 0.f, 0.f, 0.f};
  f32x4 oacc[2][4];            // O^T[d = quad*4+r][q = l16]
  float m_run[2], l_run[2];
  #pragma unroll
  for (int i = 0; i < 2; i++) {
    #pragma unroll
    for (int jd = 0; jd < 4; jd++) oacc[i][jd] = fz;
    m_run[i] = -1e30f; l_run[i] = 0.f;
  }

  const bf16* kbase = qkv + (size_t)(b * N_) * QKVN + C_ + h * HD_;
  const f16*  vbase = vt + (size_t)bh * HD_ * N_;

  // per-thread staging coords
  int kr[4], kc[4], vr[4], vc[4];
  #pragma unroll
  for (int u = 0; u < 4; u++) {
    int L = tid + u * 256;
    kr[u] = L >> 3;  kc[u] = (L & 7) * 8;
    vr[u] = L >> 4;  vc[u] = (L & 15) * 8;
  }

  // prefetch tile 0 into registers
  bf16x8 kreg[4]; f16x8 vreg[4];
  #pragma unroll
  for (int u = 0; u < 4; u++) {
    kreg[u] = *(const bf16x8*)(kbase + (size_t)kr[u] * QKVN + kc[u]);
    vreg[u] = *(const f16x8*)(vbase + (size_t)vr[u] * N_ + vc[u]);
  }

  for (int kv = 0; kv < N_; kv += 128) {
    __syncthreads();   // prior compute done reading LDS
    #pragma unroll
    for (int u = 0; u < 4; u++) {
      *(bf16x8*)(Ks + kr[u] * KSTR + kc[u]) = kreg[u];
      *(f16x8*)(Vs + vr[u] * VSTR + vc[u])  = vreg[u];
    }
    __syncthreads();

    // issue next tile's loads; they complete during compute below
    if (kv + 128 < N_) {
      #pragma unroll
      for (int u = 0; u < 4; u++) {
        kreg[u] = *(const bf16x8*)(kbase + (size_t)(kv + 128 + kr[u]) * QKVN + kc[u]);
        vreg[u] = *(const f16x8*)(vbase + (size_t)vr[u] * N_ + kv + 128 + vc[u]);
      }
    }

    // S^T = K @ Q^T
    f32x4 sv[2][8];
    #pragma unroll
    for (int i = 0; i < 2; i++)
      #pragma unroll
      for (int kf = 0; kf < 8; kf++) sv[i][kf] = fz;
    #pragma unroll
    for (int kk = 0; kk < 2; kk++) {
      #pragma unroll
      for (int kf = 0; kf < 8; kf++) {
        bf16x8 kb = *(const bf16x8*)(Ks + (kf * 16 + l16) * KSTR + kk * 32 + quad * 8);
        sv[0][kf] = __builtin_amdgcn_mfma_f32_16x16x32_bf16(kb, qf[0][kk], sv[0][kf], 0, 0, 0);
        sv[1][kf] = __builtin_amdgcn_mfma_f32_16x16x32_bf16(kb, qf[1][kk], sv[1][kf], 0, 0, 0);
      }
    }

    // online softmax: keys in regs, queries on l16
    f16x4 pb[2][8];
    #pragma unroll
    for (int i = 0; i < 2; i++) {
      float mx = sv[i][0][0];
      #pragma unroll
      for (int kf = 0; kf < 8; kf++)
        #pragma unroll
        for (int r = 0; r < 4; r++) mx = fmaxf(mx, sv[i][kf][r]);
      mx = fmaxf(mx, __shfl_xor(mx, 16));
      mx = fmaxf(mx, __shfl_xor(mx, 32));
      float mold = m_run[i];
      float mnew = fmaxf(mold, mx);
      float mb   = mnew * CEXP;
      float al   = fast_exp2(mold * CEXP - mb);
      float rs = 0.f;
      #pragma unroll
      for (int kf = 0; kf < 8; kf++) {
        #pragma unroll
        for (int r = 0; r < 4; r++) {
          float p = fast_exp2(sv[i][kf][r] * CEXP - mb);
          pb[i][kf][r] = (f16)p;
          rs += p;
        }
      }
      rs += __shfl_xor(rs, 16);
      rs += __shfl_xor(rs, 32);
      m_run[i] = mnew;
      l_run[i] = l_run[i] * al + rs;
      #pragma unroll
      for (int jd = 0; jd < 4; jd++) oacc[i][jd] *= al;
    }

    // O^T += V^T @ P^T
    #pragma unroll
    for (int kc2 = 0; kc2 < 8; kc2++) {
      #pragma unroll
      for (int jd = 0; jd < 4; jd++) {
        f16x4 va = *(const f16x4*)(Vs + (jd * 16 + l16) * VSTR + kc2 * 16 + quad * 4);
        oacc[0][jd] = __builtin_amdgcn_mfma_f32_16x16x16f16(va, pb[0][kc2], oacc[0][jd], 0, 0, 0);
        oacc[1][jd] = __builtin_amdgcn_mfma_f32_16x16x16f16(va, pb[1][kc2], oacc[1][jd], 0, 0, 0);
      }
    }
  }

  // finalize: O = O^T / l, 4B packed fp8 stores
  #pragma unroll
  for (int i = 0; i < 2; i++) {
    float inv = 1.0f / l_run[i];
    int n = q0 + wave * 32 + i * 16 + l16;
    #pragma unroll
    for (int jd = 0; jd < 4; jd++) {
      int p = to_fp8x4(oacc[i][jd][0] * inv, oacc[i][jd][1] * inv,
                       oacc[i][jd][2] * inv, oacc[i][jd][3] * inv);
      *(int*)(o + (size_t)(b * N_ + n) * C_ + h * HD_ + jd * 16 + quad * 4) = p;
    }
  }
}

// ---------------- host: workspace layout + launch ----------------
#define WQKVT_OFF  0u
#define WPROJT_OFF 1769472u
#define WFC1T_OFF  2359296u
#define WFC2T_OFF  4718592u
#define Y_OFF      7077888u
#define QKV_OFF    19660800u    // bf16 qkv (75.5 MB); aliased by fp8 hbuf (50.3 MB) after attn
#define VT_OFF     95158272u
#define O_OFF      120324096u
#define X1_OFF     132907008u
#define WS_NEEDED  183238656u

extern "C" void kernel_launch(void* const* d_in, const int* in_sizes, int n_in,
                              void* d_out, int out_size, void* d_ws, size_t ws_size,
                              hipStream_t stream) {
  if (ws_size < (size_t)WS_NEEDED) return;

  const float* x      = (const float*)d_in[0];
  const float* w_qkv  = (const float*)d_in[1];
  const float* w_proj = (const float*)d_in[2];
  const float* b_proj = (const float*)d_in[3];
  const float* ln1_g  = (const float*)d_in[4];
  const float* ln1_b  = (const float*)d_in[5];
  const float* ln2_g  = (const float*)d_in[6];
  const float* ln2_b  = (const float*)d_in[7];
  const float* ls1_g  = (const float*)d_in[8];
  const float* ls2_g  = (const float*)d_in[9];
  const float* w_fc1  = (const float*)d_in[10];
  const float* b_fc1  = (const float*)d_in[11];
  const float* w_fc2  = (const float*)d_in[12];
  const float* b_fc2  = (const float*)d_in[13];

  char* ws = (char*)d_ws;
  u8*    wqkvT  = (u8*)(ws + WQKVT_OFF);
  u8*    wprojT = (u8*)(ws + WPROJT_OFF);
  u8*    wfc1T  = (u8*)(ws + WFC1T_OFF);
  u8*    wfc2T  = (u8*)(ws + WFC2T_OFF);
  u8*    y      = (u8*)(ws + Y_OFF);
  bf16*  qkv    = (bf16*)(ws + QKV_OFF);
  u8*    hbuf   = (u8*)(ws + QKV_OFF);   // alias: qkv dead after attention
  f16*   vt     = (f16*)(ws + VT_OFF);
  u8*    o      = (u8*)(ws + O_OFF);
  float* x1     = (float*)(ws + X1_OFF);
  float* out    = (float*)d_out;

  dim3 tb(32, 8);
  transpose_cast<<<dim3(QKVN / 32, C_ / 32), tb, 0, stream>>>(w_qkv,  wqkvT,  C_,   QKVN);
  transpose_cast<<<dim3(C_   / 32, C_ / 32), tb, 0, stream>>>(w_proj, wprojT, C_,   C_);
  transpose_cast<<<dim3(MLP_ / 32, C_ / 32), tb, 0, stream>>>(w_fc1,  wfc1T,  C_,   MLP_);
  transpose_cast<<<dim3(C_ / 32, MLP_ / 32), tb, 0, stream>>>(w_fc2,  wfc2T,  MLP_, C_);

  ln_cast_kernel<<<M_, 256, 0, stream>>>(x, ln1_g, ln1_b, y);

  gemm_bt<0><<<(QKVN / 128) * 128, 256, 0, stream>>>(
      y, wqkvT, qkv, nullptr, nullptr, nullptr, M_, QKVN, C_, QKVN / 128);

  transpose_v<<<dim3(N_ / 32, HD_ / 32, B_ * H_), tb, 0, stream>>>(qkv, vt);

  attn_kernel<<<(N_ / 128) * B_ * H_, 256, 0, stream>>>(qkv, vt, o);

  gemm_bt<1><<<(C_ / 128) * 128, 256, 0, stream>>>(
      o, wprojT, x1, b_proj, ls1_g, x, M_, C_, C_, C_ / 128);

  ln_cast_kernel<<<M_, 256, 0, stream>>>(x1, ln2_g, ln2_b, y);

  gemm_bt<2><<<(MLP_ / 128) * 128, 256, 0, stream>>>(
      y, wfc1T, hbuf, b_fc1, nullptr, nullptr, M_, MLP_, C_, MLP_ / 128);

  gemm_bt<3><<<(C_ / 128) * 128, 256, 0, stream>>>(
      hbuf, wfc2T, out, b_fc2, ls2_g, x1, M_, C_, MLP_, C_ / 128);
}